// Round 10
// baseline (7892.528 us; speedup 1.0000x reference)
//
#include <hip/hip_runtime.h>
#include <math.h>

// TemporalDecoder round 10: cached activation loads + 1 acquire-fence/phase.
// R5-R9 read h/x via agent-scope (sc1) loads -> bypass L1/L2, every lane-batch
// is an LLC-fabric round trip, 64-way WG redundancy uncached => ~26us/phase of
// load-wait (the R6-R9 invariant). Now: plain cached uint4 loads; freshness via
// ONE __builtin_amdgcn_fence(ACQUIRE, "agent") (L1+L2 inv) at barrier exit.
// h-stores remain sc1 write-through (no dirty L2 lines -> no wb needed).

#define BB 256
#define SS 128
#define HH 512
#define NSTEPS 32

typedef __attribute__((ext_vector_type(8))) _Float16 f16x8;
typedef __attribute__((ext_vector_type(4))) float f32x4;

#define LO_SCALE 2048.0f
#define LO_INV   (1.0f / 2048.0f)
#define AGENT __HIP_MEMORY_SCOPE_AGENT

__device__ __forceinline__ void st_agent_u64(unsigned long long* p, unsigned long long v) {
    __hip_atomic_store(p, v, __ATOMIC_RELAXED, AGENT);
}

// Raw WG barrier: LDS ordering only, leaves global loads in flight.
__device__ __forceinline__ void wg_barrier() {
    __builtin_amdgcn_sched_barrier(0);
    asm volatile("s_waitcnt lgkmcnt(0)" ::: "memory");
    __builtin_amdgcn_s_barrier();
    asm volatile("" ::: "memory");
    __builtin_amdgcn_sched_barrier(0);
}

// ---------------- prep kernels ------------------------------------------------
__global__ __launch_bounds__(256) void xcvt(const float* __restrict__ x,
                                            ushort* __restrict__ xh, int n8) {
    int t = blockIdx.x * 256 + threadIdx.x;
    if (t >= n8) return;
    size_t i = (size_t)t * 8;
    float4 a = *(const float4*)(x + i), b = *(const float4*)(x + i + 4);
    union { _Float16 h[8]; uint4 u; } P;
    P.h[0] = (_Float16)a.x; P.h[1] = (_Float16)a.y;
    P.h[2] = (_Float16)a.z; P.h[3] = (_Float16)a.w;
    P.h[4] = (_Float16)b.x; P.h[5] = (_Float16)b.y;
    P.h[6] = (_Float16)b.z; P.h[7] = (_Float16)b.w;
    *(uint4*)(xh + i) = P.u;
}

__global__ __launch_bounds__(256) void wsplit_layers(
    const float* __restrict__ W_ih, const float* __restrict__ W_hh,
    ushort* __restrict__ wf0, ushort* __restrict__ wf1)
{
    int f = blockIdx.x * 256 + threadIdx.x;      // 0..524287
    int L = f >> 18;
    int t = f & 262143;
    int lane = t & 63;
    int kfg = (t >> 6) & 31;
    int nfrag = t >> 11;                         // 0..127
    int nloc = (nfrag & 1) * 16 + (lane & 15);
    int g = nloc & 3, hc = nloc >> 2;
    int n_W = g * 512 + (nfrag >> 1) * 8 + hc;
    int mat = kfg >> 4;
    int klocal = (kfg & 15) * 32 + (lane >> 4) * 8;
    const float* src = (mat ? W_hh : W_ih) + (size_t)L * (2048 * 512)
                       + (size_t)n_W * 512 + klocal;
    float4 a = *(const float4*)src;
    float4 b = *(const float4*)(src + 4);
    float v[8] = {a.x, a.y, a.z, a.w, b.x, b.y, b.z, b.w};
    union { _Float16 h[8]; uint4 u; } Hi, Lo;
    #pragma unroll
    for (int j = 0; j < 8; ++j) {
        Hi.h[j] = (_Float16)v[j];
        Lo.h[j] = (_Float16)((v[j] - (float)Hi.h[j]) * LO_SCALE);
    }
    ushort* dst = L ? wf1 : wf0;
    size_t b0 = (((size_t)nfrag * 2 + 0) * 32 + kfg) * 512 + lane * 8;
    size_t b1 = (((size_t)nfrag * 2 + 1) * 32 + kfg) * 512 + lane * 8;
    *(uint4*)(dst + b0) = Hi.u;
    *(uint4*)(dst + b1) = Lo.u;
}

__global__ __launch_bounds__(256) void wsplit_out(
    const float* __restrict__ W_out, ushort* __restrict__ wfO)
{
    int f = blockIdx.x * 256 + threadIdx.x;      // 0..32767
    int lane = f & 63;
    int kfg = (f >> 6) & 15;
    int nfrag = f >> 10;                         // 0..31
    int n_W = nfrag * 16 + (lane & 15);
    int klocal = kfg * 32 + (lane >> 4) * 8;
    const float* src = W_out + (size_t)n_W * 512 + klocal;
    float4 a = *(const float4*)src;
    float4 b = *(const float4*)(src + 4);
    float v[8] = {a.x, a.y, a.z, a.w, b.x, b.y, b.z, b.w};
    union { _Float16 h[8]; uint4 u; } Hi, Lo;
    #pragma unroll
    for (int j = 0; j < 8; ++j) {
        Hi.h[j] = (_Float16)v[j];
        Lo.h[j] = (_Float16)((v[j] - (float)Hi.h[j]) * LO_SCALE);
    }
    size_t b0 = (((size_t)nfrag * 2 + 0) * 16 + kfg) * 512 + lane * 8;
    size_t b1 = (((size_t)nfrag * 2 + 1) * 16 + kfg) * 512 + lane * 8;
    *(uint4*)(wfO + b0) = Hi.u;
    *(uint4*)(wfO + b1) = Lo.u;
}

// Wcomb = Wih0 @ Wout  (fp32, [2048,512] = [2048,512]@[512,512])
__global__ __launch_bounds__(256) void gemm_wcomb(
    const float* __restrict__ A, const float* __restrict__ Bm, float* __restrict__ C)
{
    __shared__ float sAf[64][17];
    __shared__ float sBf[16][65];
    const int tid = threadIdx.x;
    const int tx = tid & 15, ty = tid >> 4;
    const int n0 = blockIdx.x * 64, h0 = blockIdx.y * 64;
    float acc[4][4] = {};
    #pragma unroll 1
    for (int k0 = 0; k0 < 512; k0 += 16) {
        __syncthreads();
        {
            int r = tid >> 2, c = (tid & 3) * 4;
            float4 v = *(const float4*)&A[(size_t)(n0 + r) * 512 + k0 + c];
            sAf[r][c] = v.x; sAf[r][c + 1] = v.y; sAf[r][c + 2] = v.z; sAf[r][c + 3] = v.w;
        }
        {
            int r = tid >> 4, c = (tid & 15) * 4;
            float4 v = *(const float4*)&Bm[(size_t)(k0 + r) * 512 + h0 + c];
            sBf[r][c] = v.x; sBf[r][c + 1] = v.y; sBf[r][c + 2] = v.z; sBf[r][c + 3] = v.w;
        }
        __syncthreads();
        #pragma unroll
        for (int kk = 0; kk < 16; ++kk) {
            #pragma unroll
            for (int a_ = 0; a_ < 4; ++a_) {
                float av = sAf[ty + 16 * a_][kk];
                #pragma unroll
                for (int b_ = 0; b_ < 4; ++b_)
                    acc[a_][b_] += av * sBf[kk][tx + 16 * b_];
            }
        }
    }
    #pragma unroll
    for (int a_ = 0; a_ < 4; ++a_)
        #pragma unroll
        for (int b_ = 0; b_ < 4; ++b_)
            C[(size_t)(n0 + ty + 16 * a_) * 512 + h0 + tx + 16 * b_] = acc[a_][b_];
}

__global__ __launch_bounds__(256) void bcomb_k(const float* __restrict__ Wih0,
                                               const float* __restrict__ bout,
                                               float* __restrict__ bc) {
    int n = blockIdx.x * 256 + threadIdx.x;
    float a = 0.f;
    for (int f = 0; f < 512; ++f) a += Wih0[(size_t)n * 512 + f] * bout[f];
    bc[n] = a;
}

// split Wcomb to frag order (mirrors wf0's Wih half: kfg 0..15)
__global__ __launch_bounds__(256) void wsplit_wcomb(
    const float* __restrict__ wc, ushort* __restrict__ wfC)
{
    int f = blockIdx.x * 256 + threadIdx.x;      // 0..131071
    int lane = f & 63;
    int kfg = (f >> 6) & 15;
    int nfrag = f >> 10;                         // 0..127
    int nloc = (nfrag & 1) * 16 + (lane & 15);
    int g = nloc & 3, hc = nloc >> 2;
    int n_W = g * 512 + (nfrag >> 1) * 8 + hc;
    int klocal = kfg * 32 + (lane >> 4) * 8;
    const float* src = wc + (size_t)n_W * 512 + klocal;
    float4 a = *(const float4*)src;
    float4 b = *(const float4*)(src + 4);
    float v[8] = {a.x, a.y, a.z, a.w, b.x, b.y, b.z, b.w};
    union { _Float16 h[8]; uint4 u; } Hi, Lo;
    #pragma unroll
    for (int j = 0; j < 8; ++j) {
        Hi.h[j] = (_Float16)v[j];
        Lo.h[j] = (_Float16)((v[j] - (float)Hi.h[j]) * LO_SCALE);
    }
    size_t b0 = (((size_t)nfrag * 2 + 0) * 16 + kfg) * 512 + lane * 8;
    size_t b1 = (((size_t)nfrag * 2 + 1) * 16 + kfg) * 512 + lane * 8;
    *(uint4*)(wfC + b0) = Hi.u;
    *(uint4*)(wfC + b1) = Lo.u;
}

// ---------------- grid barrier: store + per-wave __all scan + acquire ---------
__device__ __forceinline__ void gridbar(unsigned* slots, unsigned phase)
{
    __syncthreads();   // drains vmcnt: this WG's sc1 h-stores acked at LLC
    if (threadIdx.x == 0)
        __hip_atomic_store(&slots[blockIdx.x], phase, __ATOMIC_RELAXED, AGENT);
    // thread tid polls slots[tid]; the 4 waves partition all 256 slots.
    unsigned v;
    do {
        v = __hip_atomic_load(&slots[threadIdx.x], __ATOMIC_RELAXED, AGENT);
    } while (!__all((int)(v >= phase)));
    // ONE L1+L2 invalidate per phase: subsequent plain loads see fresh h.
    __builtin_amdgcn_fence(__ATOMIC_ACQUIRE, "agent");
    __syncthreads();
}

// ---------------- LSTM cell (M=128 x N=32 gate-cols, K=1024) ------------------
static __device__ __forceinline__ void run_cell(
    const int tid, const int mblk, const int hcblk,
    const ushort* __restrict__ Asrc, const size_t ldA,
    const ushort* __restrict__ Hprev,
    ushort (*sW)[2][32][512], ushort (*sA)[128][64],
    float (&cReg)[16], const float bias, ushort* __restrict__ Hout)
{
    const int lane = tid & 63, wid = tid >> 6;
    const int wm = wid >> 1, wn = wid & 1;
    const int lr = lane & 15, lq = lane >> 4;

    f32x4 acch[4], accl[4];
    #pragma unroll
    for (int i = 0; i < 4; ++i) {
        acch[i] = (f32x4){bias, bias, bias, bias};
        accl[i] = (f32x4){0.f, 0.f, 0.f, 0.f};
    }

    const int srow = tid >> 1;
    const int cbase = (tid & 1) * 4;
    uint4 ur[3][4];

    auto ld = [&](int it) {
        const int k0 = (it & 7) * 64;
        const ushort* s = (it < 8)
            ? (Asrc + (size_t)(mblk * 128 + srow) * ldA + k0 + cbase * 8)
            : (Hprev + (size_t)(mblk * 128 + srow) * 512 + k0 + cbase * 8);
        const uint4* s4 = (const uint4*)s;
        uint4* u = ur[it % 3];
        #pragma unroll
        for (int c = 0; c < 4; ++c) u[c] = s4[c];     // plain cached 16B loads
    };
    auto wr = [&](int it) {
        const uint4* u = ur[it % 3];
        ushort (*dst)[64] = sA[it & 1];
        #pragma unroll
        for (int c = 0; c < 4; ++c)
            *(uint4*)&dst[srow][((cbase + c) ^ (srow & 7)) * 8] = u[c];
    };
    auto compute = [&](int it) {
        ushort (*buf)[64] = sA[it & 1];
        #pragma unroll
        for (int kf = 0; kf < 2; ++kf) {
            const int kfg = it * 2 + kf;
            const f16x8 bh = *(const f16x8*)&sW[wn][0][kfg][lane * 8];
            const f16x8 bl = *(const f16x8*)&sW[wn][1][kfg][lane * 8];
            #pragma unroll
            for (int mf = 0; mf < 4; ++mf) {
                const int row = wm * 64 + mf * 16 + lr;
                const int cg = kf * 4 + lq;
                const f16x8 a = *(const f16x8*)&buf[row][(cg ^ (row & 7)) * 8];
                acch[mf] = __builtin_amdgcn_mfma_f32_16x16x32_f16(a, bh, acch[mf], 0, 0, 0);
                accl[mf] = __builtin_amdgcn_mfma_f32_16x16x32_f16(a, bl, accl[mf], 0, 0, 0);
            }
        }
    };

    ld(0); ld(1); ld(2);
    wr(0);
    #pragma unroll
    for (int it = 0; it < 16; ++it) {
        wg_barrier();                    // sA[it&1] ready; ring loads stay in flight
        if (it + 3 < 16) ld(it + 3);
        compute(it);
        if (it + 1 < 16) wr(it + 1);     // vmcnt wait sits after compute
    }

    // epilogue: all 4 gate-lanes compute identical (cn,hn); pack 4 hcols -> 8B store
    const int nloc = wn * 16 + lr;
    const int g = nloc & 3;
    const int colbase = hcblk * 8 + wn * 4;
    #pragma unroll
    for (int mf = 0; mf < 4; ++mf) {
        #pragma unroll
        for (int j = 0; j < 4; ++j) {
            float v = acch[mf][j] + accl[mf][j] * LO_INV;
            float s1 = __shfl_xor(v, 1, 64);
            float s2 = __shfl_xor(v, 2, 64);
            float s3 = __shfl_xor(v, 3, 64);
            float sel0 = v;
            auto selk = [&](int k) {
                return (k == 0) ? sel0 : (k == 1) ? s1 : (k == 2) ? s2 : s3;
            };
            float pi = selk(g), pf = selk(g ^ 1), pg = selk(g ^ 2), po = selk(g ^ 3);
            float ig = 1.f / (1.f + __expf(-pi));
            float fg = 1.f / (1.f + __expf(-pf));
            float e2g = __expf(2.f * fminf(fmaxf(pg, -20.f), 20.f));
            float gg = (e2g - 1.f) / (e2g + 1.f);
            float og = 1.f / (1.f + __expf(-po));
            float cn = fg * cReg[mf * 4 + j] + ig * gg;
            cReg[mf * 4 + j] = cn;
            float e2c = __expf(2.f * fminf(fmaxf(cn, -20.f), 20.f));
            float th = (e2c - 1.f) / (e2c + 1.f);
            float hn = og * th;
            union { _Float16 h; ushort u; } P;
            P.h = (_Float16)hn;
            int hb = (int)P.u;
            int base = lane & ~15;
            int b1 = __shfl(hb, base + 4, 64);
            int b2 = __shfl(hb, base + 8, 64);
            int b3 = __shfl(hb, base + 12, 64);
            if (lr == 0) {
                unsigned long long pk =
                    (unsigned long long)(unsigned)(hb & 0xFFFF)
                    | ((unsigned long long)(unsigned)(b1 & 0xFFFF) << 16)
                    | ((unsigned long long)(unsigned)(b2 & 0xFFFF) << 32)
                    | ((unsigned long long)(unsigned)(b3 & 0xFFFF) << 48);
                int row = mblk * 128 + wm * 64 + mf * 16 + lq * 4 + j;
                st_agent_u64((unsigned long long*)&Hout[(size_t)row * 512 + colbase], pk);
            }
        }
    }
}

// ---------------- fc: out[:,s] = h1 @ Wout^T + bout (half1 WGs, decode) -------
static __device__ __forceinline__ void run_fc(
    const int tid, const int w,
    const ushort* __restrict__ h1, const ushort* __restrict__ wfO,
    const float* __restrict__ b_out, float* __restrict__ out, const int s)
{
    const int lane = tid & 63, wid = tid >> 6;
    const int wm = wid >> 1, wn = wid & 1;
    const int lr = lane & 15, lq = lane >> 4;
    const int fm = w & 7, fn = w >> 3;
    const int nfrag = fn * 2 + wn;
    const int col = nfrag * 16 + lr;
    const int arow = fm * 32 + wm * 16 + lr;

    float bv = b_out[col];
    f32x4 acch = (f32x4){bv, bv, bv, bv};
    f32x4 accl = (f32x4){0.f, 0.f, 0.f, 0.f};

    uint4 au[16];
    #pragma unroll
    for (int kfg = 0; kfg < 16; ++kfg)
        au[kfg] = *(const uint4*)&h1[(size_t)arow * 512 + kfg * 32 + lq * 8];
    #pragma unroll
    for (int kfg = 0; kfg < 16; ++kfg) {
        union { uint4 u; f16x8 v; } A;
        A.u = au[kfg];
        const f16x8 bh = *(const f16x8*)&wfO[(((size_t)nfrag * 2 + 0) * 16 + kfg) * 512 + lane * 8];
        const f16x8 bl = *(const f16x8*)&wfO[(((size_t)nfrag * 2 + 1) * 16 + kfg) * 512 + lane * 8];
        acch = __builtin_amdgcn_mfma_f32_16x16x32_f16(A.v, bh, acch, 0, 0, 0);
        accl = __builtin_amdgcn_mfma_f32_16x16x32_f16(A.v, bl, accl, 0, 0, 0);
    }
    #pragma unroll
    for (int j = 0; j < 4; ++j) {
        float v = acch[j] + accl[j] * LO_INV;
        int row = fm * 32 + wm * 16 + lq * 4 + j;
        out[(size_t)row * (NSTEPS * 512) + (size_t)s * 512 + col] = v;
    }
}

// ---------------- persistent kernel ------------------------------------------
__global__ __launch_bounds__(256, 1) void persist(
    const ushort* __restrict__ xh,
    const ushort* __restrict__ wf0, const ushort* __restrict__ wf1,
    const ushort* __restrict__ wfO, const ushort* __restrict__ wfC,
    const float* __restrict__ b_ih, const float* __restrict__ b_hh,
    const float* __restrict__ b_out, const float* __restrict__ bcomb,
    ushort* h0a, ushort* h0b, ushort* h1a, ushort* h1b,
    float* out, unsigned* slots)
{
    __shared__ ushort sW[2][2][32][512];      // 128KB
    __shared__ ushort sA[2][128][64];         // 32KB

    const int tid = threadIdx.x;
    const int blk = blockIdx.x;
    const int half = blk >> 7;
    const int w = blk & 127;
    const int mblk = w >> 6, hcblk = w & 63;

    {
        const uint4* srcv = (const uint4*)((half ? wf1 : wf0) + (size_t)hcblk * 65536);
        uint4* dstv = (uint4*)&sW[0][0][0][0];
        #pragma unroll 1
        for (int i = tid; i < 8192; i += 256) dstv[i] = srcv[i];
    }

    float cReg[16];
    #pragma unroll
    for (int i = 0; i < 16; ++i) cReg[i] = 0.f;

    const int lane = tid & 63, wid = tid >> 6, wn = wid & 1;
    const int nloc = wn * 16 + (lane & 15);
    const int g = nloc & 3, hc = nloc >> 2;
    const int gcol = g * 512 + hcblk * 8 + hc;
    const float bias = b_ih[half * 2048 + gcol] + b_hh[half * 2048 + gcol];
    __syncthreads();

    ushort* h0buf[2] = {h0a, h0b};
    ushort* h1buf[2] = {h1a, h1b};
    unsigned nbar = 0;

    // ---- encode: 129 phases, layer-pipelined ----
    #pragma unroll 1
    for (int p = 0; p <= SS; ++p) {
        if (half == 0) {
            if (p < SS)
                run_cell(tid, mblk, hcblk, xh + (size_t)p * 512, (size_t)(SS * 512),
                         h0buf[p & 1], sW, sA, cReg, bias, h0buf[(p + 1) & 1]);
        } else {
            if (p >= 1) {
                int q = p - 1;
                run_cell(tid, mblk, hcblk, h0buf[p & 1], 512,
                         h1buf[q & 1], sW, sA, cReg, bias, h1buf[(q + 1) & 1]);
            }
        }
        gridbar(slots, ++nbar);
    }
    int h0cur = 0, h1cur = 0;

    // ---- transition: half0 swaps Wih0 -> Wcomb in LDS; bias += bcomb ----
    float biasDec = bias;
    if (half == 0) {
        const uint4* srcv = (const uint4*)(wfC + (size_t)hcblk * 32768);
        #pragma unroll 1
        for (int i = tid; i < 4096; i += 256) {
            int l8 = i & 63;
            int rest = i >> 6;          // (nf*2+pp)*16 + kfg
            int kfg = rest & 15, pp = (rest >> 4) & 1, nf = rest >> 5;
            *((uint4*)&sW[nf][pp][kfg][0] + l8) = srcv[i];
        }
        biasDec = bias + bcomb[gcol];
        __syncthreads();
    }

    // ---- decode: 2 phases/step (L0' || fc-out, then L1) ----
    #pragma unroll 1
    for (int s = 0; s < NSTEPS; ++s) {
        if (half == 0) {
            if (s < NSTEPS - 1)
                run_cell(tid, mblk, hcblk, h1buf[h1cur], 512, h0buf[h0cur],
                         sW, sA, cReg, biasDec, h0buf[h0cur ^ 1]);
        } else {
            run_fc(tid, w, h1buf[h1cur], wfO, b_out, out, s);
        }
        gridbar(slots, ++nbar);
        h0cur ^= 1;
        if (s == NSTEPS - 1) break;
        if (half == 1)
            run_cell(tid, mblk, hcblk, h0buf[h0cur], 512, h1buf[h1cur],
                     sW, sA, cReg, bias, h1buf[h1cur ^ 1]);
        gridbar(slots, ++nbar);
        h1cur ^= 1;
    }
}

// ---------------- host ---------------------------------------------------------
extern "C" void kernel_launch(void* const* d_in, const int* in_sizes, int n_in,
                              void* d_out, int out_size, void* d_ws, size_t ws_size,
                              hipStream_t stream)
{
    const float* x     = (const float*)d_in[0];
    const float* W_ih  = (const float*)d_in[1];
    const float* W_hh  = (const float*)d_in[2];
    const float* b_ih  = (const float*)d_in[3];
    const float* b_hh  = (const float*)d_in[4];
    const float* W_out = (const float*)d_in[5];
    const float* b_out = (const float*)d_in[6];
    float* out = (float*)d_out;
    (void)n_in; (void)out_size; (void)ws_size;

    char* ws = (char*)d_ws;
    ushort*   h0a   = (ushort*)(ws + 0);
    ushort*   h0b   = (ushort*)(ws + 262144);
    ushort*   h1a   = (ushort*)(ws + 524288);
    ushort*   h1b   = (ushort*)(ws + 786432);
    unsigned* slots = (unsigned*)(ws + 1048576);
    float*    bcomb = (float*)(ws + 1049600);
    const size_t ZBYTES = 1057792;
    ushort* xh    = (ushort*)(ws + 1057792);                 // 33.5MB
    ushort* wf0   = (ushort*)(ws + 1057792 + 33554432);
    ushort* wf1   = (ushort*)(ws + 1057792 + 33554432 + 8388608);
    ushort* wfO   = (ushort*)(ws + 1057792 + 33554432 + 2 * 8388608);
    float*  wcomb = (float*) (ws + 1057792 + 33554432 + 2 * 8388608 + 1048576);
    ushort* wfC   = (ushort*)(ws + 1057792 + 33554432 + 2 * 8388608 + 1048576 + 4194304);
    // total ws use ~58MB

    (void)hipMemsetAsync(d_ws, 0, ZBYTES, stream);
    {
        int n8 = (in_sizes[0] + 7) / 8;                      // 2,097,152
        int blocks = (n8 + 255) / 256;                       // 8192
        xcvt<<<blocks, 256, 0, stream>>>(x, xh, n8);
    }
    wsplit_layers<<<2048, 256, 0, stream>>>(W_ih, W_hh, wf0, wf1);
    wsplit_out<<<128, 256, 0, stream>>>(W_out, wfO);
    gemm_wcomb<<<dim3(32, 8), 256, 0, stream>>>(W_ih, W_out, wcomb);
    bcomb_k<<<8, 256, 0, stream>>>(W_ih, b_out, bcomb);
    wsplit_wcomb<<<512, 256, 0, stream>>>(wcomb, wfC);

    persist<<<dim3(256), dim3(256), 0, stream>>>(
        xh, wf0, wf1, wfO, wfC, b_ih, b_hh, b_out, bcomb,
        h0a, h0b, h1a, h1b, out, slots);
}

// Round 13
// 5905.441 us; speedup vs baseline: 1.3365x; 1.3365x over previous
//
#include <hip/hip_runtime.h>
#include <math.h>

// TemporalDecoder round 13: R12's XCD-local design with PROVEN coherence
// primitives. R12 hung because the hand-rolled sc0 poll could hit a stale
// (no-snoop) L1 line forever. Now: barrier = per-XCD store+scan with
// __hip_atomic_* AGENT (R9's proven pattern); h data loads = __hip_atomic_load
// AGENT (R5-R9 proven); h stores plain (dirty in local L2, same-XCD readers).

#define SS 128
#define NSTEPS 32
#define T 32

typedef __attribute__((ext_vector_type(8))) _Float16 f16x8;
typedef __attribute__((ext_vector_type(4))) float f32x4;

#define LO_SCALE 2048.0f
#define LO_INV   (1.0f / 2048.0f)
#define AGENT __HIP_MEMORY_SCOPE_AGENT

__device__ __forceinline__ uint2 ld_agent_u2(const uint2* p) {
    return __hip_atomic_load(p, __ATOMIC_RELAXED, AGENT);
}

// ---------------- prep: frag-split 5 K=512 matrices --------------------------
// layout dst[cs 0..31][wn 0..3][p 0..1][kfg 0..15][lane 0..63][8]
__global__ __launch_bounds__(256) void wsplit5(
    const float* __restrict__ W_ih, const float* __restrict__ W_hh,
    const float* __restrict__ wcomb,
    ushort* __restrict__ wih0, ushort* __restrict__ whh0,
    ushort* __restrict__ wih1, ushort* __restrict__ whh1,
    ushort* __restrict__ wcmb)
{
    int f = blockIdx.x * 256 + threadIdx.x;      // 5 * 131072
    int mat = f >> 17;
    int t = f & 131071;
    int lane = t & 63;
    int kfg = (t >> 6) & 15;
    int wn = (t >> 10) & 3;
    int cs = t >> 12;
    int nloc = lane & 15;
    int g = nloc & 3, hcl = nloc >> 2;
    int n_W = g * 512 + cs * 16 + wn * 4 + hcl;
    int k = kfg * 32 + (lane >> 4) * 8;
    const float* src; ushort* dst;
    const size_t L1OFF = (size_t)2048 * 512;
    switch (mat) {
      case 0: src = W_ih + (size_t)n_W * 512 + k;         dst = wih0; break;
      case 1: src = W_hh + (size_t)n_W * 512 + k;         dst = whh0; break;
      case 2: src = W_ih + L1OFF + (size_t)n_W * 512 + k; dst = wih1; break;
      case 3: src = W_hh + L1OFF + (size_t)n_W * 512 + k; dst = whh1; break;
      default: src = wcomb + (size_t)n_W * 512 + k;       dst = wcmb; break;
    }
    float4 a = *(const float4*)src;
    float4 b = *(const float4*)(src + 4);
    float v[8] = {a.x, a.y, a.z, a.w, b.x, b.y, b.z, b.w};
    union { _Float16 h[8]; uint4 u; } Hi, Lo;
    #pragma unroll
    for (int j = 0; j < 8; ++j) {
        Hi.h[j] = (_Float16)v[j];
        Lo.h[j] = (_Float16)((v[j] - (float)Hi.h[j]) * LO_SCALE);
    }
    size_t b0 = ((((size_t)cs * 4 + wn) * 2 + 0) * 16 + kfg) * 512 + lane * 8;
    size_t b1 = ((((size_t)cs * 4 + wn) * 2 + 1) * 16 + kfg) * 512 + lane * 8;
    *(uint4*)(dst + b0) = Hi.u;
    *(uint4*)(dst + b1) = Lo.u;
}

// Wout frag: [cs][p][kfg][lane][8]; out-col = cs*16 + (lane&15)
__global__ __launch_bounds__(256) void wsplit_o(
    const float* __restrict__ W_out, ushort* __restrict__ wfO)
{
    int f = blockIdx.x * 256 + threadIdx.x;      // 32768
    int lane = f & 63;
    int kfg = (f >> 6) & 15;
    int cs = f >> 10;
    int col = cs * 16 + (lane & 15);
    int k = kfg * 32 + (lane >> 4) * 8;
    const float* src = W_out + (size_t)col * 512 + k;
    float4 a = *(const float4*)src;
    float4 b = *(const float4*)(src + 4);
    float v[8] = {a.x, a.y, a.z, a.w, b.x, b.y, b.z, b.w};
    union { _Float16 h[8]; uint4 u; } Hi, Lo;
    #pragma unroll
    for (int j = 0; j < 8; ++j) {
        Hi.h[j] = (_Float16)v[j];
        Lo.h[j] = (_Float16)((v[j] - (float)Hi.h[j]) * LO_SCALE);
    }
    size_t b0 = (((size_t)cs * 2 + 0) * 16 + kfg) * 512 + lane * 8;
    size_t b1 = (((size_t)cs * 2 + 1) * 16 + kfg) * 512 + lane * 8;
    *(uint4*)(wfO + b0) = Hi.u;
    *(uint4*)(wfO + b1) = Lo.u;
}

// Wcomb = Wih0 @ Wout (fp32) -- proven in R9
__global__ __launch_bounds__(256) void gemm_wcomb(
    const float* __restrict__ A, const float* __restrict__ Bm, float* __restrict__ C)
{
    __shared__ float sAf[64][17];
    __shared__ float sBf[16][65];
    const int tid = threadIdx.x;
    const int tx = tid & 15, ty = tid >> 4;
    const int n0 = blockIdx.x * 64, h0 = blockIdx.y * 64;
    float acc[4][4] = {};
    #pragma unroll 1
    for (int k0 = 0; k0 < 512; k0 += 16) {
        __syncthreads();
        {
            int r = tid >> 2, c = (tid & 3) * 4;
            float4 v = *(const float4*)&A[(size_t)(n0 + r) * 512 + k0 + c];
            sAf[r][c] = v.x; sAf[r][c+1] = v.y; sAf[r][c+2] = v.z; sAf[r][c+3] = v.w;
        }
        {
            int r = tid >> 4, c = (tid & 15) * 4;
            float4 v = *(const float4*)&Bm[(size_t)(k0 + r) * 512 + h0 + c];
            sBf[r][c] = v.x; sBf[r][c+1] = v.y; sBf[r][c+2] = v.z; sBf[r][c+3] = v.w;
        }
        __syncthreads();
        #pragma unroll
        for (int kk = 0; kk < 16; ++kk)
            #pragma unroll
            for (int a_ = 0; a_ < 4; ++a_) {
                float av = sAf[ty + 16*a_][kk];
                #pragma unroll
                for (int b_ = 0; b_ < 4; ++b_)
                    acc[a_][b_] += av * sBf[kk][tx + 16*b_];
            }
    }
    #pragma unroll
    for (int a_ = 0; a_ < 4; ++a_)
        #pragma unroll
        for (int b_ = 0; b_ < 4; ++b_)
            C[(size_t)(n0 + ty + 16*a_) * 512 + h0 + tx + 16*b_] = acc[a_][b_];
}

__global__ __launch_bounds__(256) void bcomb_k(const float* __restrict__ Wih0,
                                               const float* __restrict__ bout,
                                               float* __restrict__ bc) {
    int n = blockIdx.x * 256 + threadIdx.x;
    float a = 0.f;
    for (int f = 0; f < 512; ++f) a += Wih0[(size_t)n * 512 + f] * bout[f];
    bc[n] = a;
}

// ---------------- device helpers ---------------------------------------------
__device__ __forceinline__ void wgbar() {
    __builtin_amdgcn_sched_barrier(0);
    asm volatile("s_waitcnt lgkmcnt(0)" ::: "memory");
    __builtin_amdgcn_s_barrier();
    asm volatile("" ::: "memory");
    __builtin_amdgcn_sched_barrier(0);
}

// intra-XCD barrier: per-WG slot store + wave0 scan of the XCD's 32 slots.
// R9's proven no-RMW pattern, scoped to 32 WGs.
__device__ __forceinline__ void xbar(unsigned* slots, unsigned phase, int cs) {
    __syncthreads();                     // drains vmcnt: h-stores are in L2
    if (threadIdx.x == 0)
        __hip_atomic_store(&slots[cs], phase, __ATOMIC_RELAXED, AGENT);
    if (threadIdx.x < 64) {              // wave 0: lanes 0..31 poll 32 slots
        unsigned v;
        do {
            v = (threadIdx.x < 32)
                ? __hip_atomic_load(&slots[threadIdx.x], __ATOMIC_RELAXED, AGENT)
                : phase;
        } while (!__all((int)(v >= phase)));
    }
    __syncthreads();
}

// stage one 256-k chunk of a 32-row A into sA[buf], XOR-swizzled
template<bool CVT>
__device__ __forceinline__ void stageChunk(
    ushort (*sA)[32][256], int buf, const void* src, size_t ldSrc, int k0)
{
    const int t = threadIdx.x;
    const int row = t >> 3;
    const int cg0 = (t & 7) * 4;
    #pragma unroll
    for (int q = 0; q < 4; ++q) {
        int cg = cg0 + q;
        int slot = (cg & 24) | ((cg ^ row) & 7);
        ushort* d = &sA[buf][row][0] + slot * 8;
        if constexpr (CVT) {
            const float* s = (const float*)src + (size_t)row * ldSrc + k0 + cg * 8;
            f32x4 f0 = *(const f32x4*)s;
            f32x4 f1 = *(const f32x4*)(s + 4);
            union { _Float16 h[8]; uint4 u; } P;
            P.h[0]=(_Float16)f0.x; P.h[1]=(_Float16)f0.y;
            P.h[2]=(_Float16)f0.z; P.h[3]=(_Float16)f0.w;
            P.h[4]=(_Float16)f1.x; P.h[5]=(_Float16)f1.y;
            P.h[6]=(_Float16)f1.z; P.h[7]=(_Float16)f1.w;
            *(uint4*)d = P.u;
        } else {
            const ushort* s = (const ushort*)src + (size_t)row * ldSrc + k0 + cg * 8;
            uint2 a = ld_agent_u2((const uint2*)s);
            uint2 b = ld_agent_u2((const uint2*)s + 1);
            uint4 wv; wv.x = a.x; wv.y = a.y; wv.z = b.x; wv.w = b.y;
            *(uint4*)d = wv;
        }
    }
}

// ---------------- the unified LSTM/fc step ------------------------------------
// gates = bias + B1(K=512)@A1 + B2(K=512)@A2 ; cell ; optional fc from A1(=h1)
template<bool A1CVT, bool B1LDS, bool FC, bool CARRY>
__device__ __forceinline__ void do_step(
    const void* A1, size_t ld1, const ushort* A2,
    const ushort* B1s, const ushort* B2s,
    ushort (*sW)[2][16][512], ushort (*sA)[32][256],
    float biasv, float* cReg, ushort* Hout, ushort* Hcarry,
    const ushort* wfO_cs, float bofc, float* outp, int s, int xrow0,
    int lane, int wn, int cs)
{
    const int lr = lane & 15, lq = lane >> 4;
    f32x4 acch[2], accl[2], fch, fcl;
    #pragma unroll
    for (int m = 0; m < 2; ++m) {
        acch[m] = (f32x4){biasv, biasv, biasv, biasv};
        accl[m] = (f32x4){0.f, 0.f, 0.f, 0.f};
    }
    if constexpr (FC) {
        fch = (f32x4){bofc, bofc, bofc, bofc};
        fcl = (f32x4){0.f, 0.f, 0.f, 0.f};
    }

    if constexpr (A1CVT) stageChunk<true>(sA, 0, A1, ld1, 0);
    else                 stageChunk<false>(sA, 0, A1, ld1, 0);

    #pragma unroll
    for (int c = 0; c < 4; ++c) {
        wgbar();                          // sA[c&1] ready
        if (c < 3) {
            int nc = c + 1, buf = nc & 1;
            if (nc < 2) {
                if constexpr (A1CVT) stageChunk<true>(sA, buf, A1, ld1, nc * 256);
                else                 stageChunk<false>(sA, buf, A1, ld1, nc * 256);
            } else {
                stageChunk<false>(sA, buf, A2, 512, (nc - 2) * 256);
            }
        }
        const int bufc = c & 1;
        #pragma unroll
        for (int kf = 0; kf < 8; ++kf) {
            const int kfg = (c & 1) * 8 + kf;
            f16x8 bh, bl;
            if (c < 2) {
                if constexpr (B1LDS) {
                    bh = *(const f16x8*)&sW[wn][0][kfg][lane * 8];
                    bl = *(const f16x8*)&sW[wn][1][kfg][lane * 8];
                } else {
                    bh = *(const f16x8*)(B1s + (((size_t)wn * 2 + 0) * 16 + kfg) * 512 + lane * 8);
                    bl = *(const f16x8*)(B1s + (((size_t)wn * 2 + 1) * 16 + kfg) * 512 + lane * 8);
                }
            } else {
                bh = *(const f16x8*)(B2s + (((size_t)wn * 2 + 0) * 16 + kfg) * 512 + lane * 8);
                bl = *(const f16x8*)(B2s + (((size_t)wn * 2 + 1) * 16 + kfg) * 512 + lane * 8);
            }
            #pragma unroll
            for (int m = 0; m < 2; ++m) {
                int row = m * 16 + lr;
                int cg = kf * 4 + lq;
                int slot = (cg & 24) | ((cg ^ row) & 7);
                f16x8 a = *(const f16x8*)(&sA[bufc][row][0] + slot * 8);
                acch[m] = __builtin_amdgcn_mfma_f32_16x16x32_f16(a, bh, acch[m], 0, 0, 0);
                accl[m] = __builtin_amdgcn_mfma_f32_16x16x32_f16(a, bl, accl[m], 0, 0, 0);
            }
            if constexpr (FC) {
                if (wn < 2 && c < 2) {
                    int kfgG = c * 8 + kf;
                    f16x8 oh = *(const f16x8*)(wfO_cs + ((size_t)0 * 16 + kfgG) * 512 + lane * 8);
                    f16x8 ol = *(const f16x8*)(wfO_cs + ((size_t)1 * 16 + kfgG) * 512 + lane * 8);
                    int row = wn * 16 + lr;
                    int cg = kf * 4 + lq;
                    int slot = (cg & 24) | ((cg ^ row) & 7);
                    f16x8 a = *(const f16x8*)(&sA[bufc][row][0] + slot * 8);
                    fch = __builtin_amdgcn_mfma_f32_16x16x32_f16(a, oh, fch, 0, 0, 0);
                    fcl = __builtin_amdgcn_mfma_f32_16x16x32_f16(a, ol, fcl, 0, 0, 0);
                }
            }
        }
    }

    // cell epilogue
    const int nloc = lane & 15;
    const int g = nloc & 3;
    const int colb = cs * 16 + wn * 4;
    #pragma unroll
    for (int m = 0; m < 2; ++m) {
        #pragma unroll
        for (int j = 0; j < 4; ++j) {
            float v = acch[m][j] + accl[m][j] * LO_INV;
            float s1 = __shfl_xor(v, 1, 64);
            float s2 = __shfl_xor(v, 2, 64);
            float s3 = __shfl_xor(v, 3, 64);
            float sel0 = v;
            auto selk = [&](int k) { return (k==0)?sel0:(k==1)?s1:(k==2)?s2:s3; };
            float pi = selk(g), pf = selk(g ^ 1), pg = selk(g ^ 2), po = selk(g ^ 3);
            float ig = 1.f / (1.f + __expf(-pi));
            float fg = 1.f / (1.f + __expf(-pf));
            float e2g = __expf(2.f * fminf(fmaxf(pg, -20.f), 20.f));
            float gg = (e2g - 1.f) / (e2g + 1.f);
            float og = 1.f / (1.f + __expf(-po));
            float cn = fg * cReg[m * 4 + j] + ig * gg;
            cReg[m * 4 + j] = cn;
            float e2c = __expf(2.f * fminf(fmaxf(cn, -20.f), 20.f));
            float th = (e2c - 1.f) / (e2c + 1.f);
            float hn = og * th;
            union { _Float16 h; ushort u; } P; P.h = (_Float16)hn;
            int hb = (int)P.u;
            int base = lane & ~15;
            int b1 = __shfl(hb, base + 4, 64);
            int b2 = __shfl(hb, base + 8, 64);
            int b3 = __shfl(hb, base + 12, 64);
            if (lr == 0) {
                unsigned long long pk =
                    (unsigned long long)(unsigned)(hb & 0xFFFF)
                    | ((unsigned long long)(unsigned)(b1 & 0xFFFF) << 16)
                    | ((unsigned long long)(unsigned)(b2 & 0xFFFF) << 32)
                    | ((unsigned long long)(unsigned)(b3 & 0xFFFF) << 48);
                int row = m * 16 + lq * 4 + j;
                *(unsigned long long*)&Hout[(size_t)row * 512 + colb] = pk;
                if constexpr (CARRY)
                    *(unsigned long long*)&Hcarry[(size_t)row * 512 + colb] = pk;
            }
        }
    }
    if constexpr (FC) {
        if (wn < 2) {
            #pragma unroll
            for (int j = 0; j < 4; ++j) {
                float v = fch[j] + fcl[j] * LO_INV;
                int row = wn * 16 + lq * 4 + j;
                outp[((size_t)(xrow0 + row) * NSTEPS + s) * 512 + cs * 16 + lr] = v;
            }
        }
    }
}

// ---------------- persistent kernel ------------------------------------------
__global__ __launch_bounds__(256, 1) void persist(
    const float* __restrict__ x,
    const ushort* __restrict__ wih0f, const ushort* __restrict__ whh0f,
    const ushort* __restrict__ wih1f, const ushort* __restrict__ whh1f,
    const ushort* __restrict__ wcombf, const ushort* __restrict__ wfOf,
    const float* __restrict__ b_ih, const float* __restrict__ b_hh,
    const float* __restrict__ b_out, const float* __restrict__ bcomb,
    ushort* h0c_all, ushort* h1_all,
    float* out, unsigned* roster, unsigned* bar)
{
    __shared__ ushort sW[4][2][16][512];      // 128KB: [wn][p][kfg][lane*8]
    __shared__ ushort sA[2][32][256];         // 32KB, dbuf, swizzled

    const int tid = threadIdx.x;
    // roster: discover XCD, claim col-slice (sA used as scratch for broadcast)
    if (tid == 0) {
        int xid;
        asm volatile("s_getreg_b32 %0, hwreg(HW_REG_XCC_ID)" : "=s"(xid));
        xid &= 7;
        unsigned slot = atomicAdd(&roster[xid * 16], 1u) & 31u;
        *(int*)&sA[0][0][0] = xid * 32 + (int)slot;
    }
    __syncthreads();
    const int packed = *(const int*)&sA[0][0][0];
    __syncthreads();
    const int xcd = packed >> 5, cs = packed & 31;
    const int xrow0 = xcd * 32;

    ushort* h0c = h0c_all + (size_t)xcd * 33 * 32 * 512;
    ushort* h1r = h1_all + (size_t)xcd * 2 * 32 * 512;
    unsigned* slots = bar + xcd * 32;

    const int lane = tid & 63, wn = tid >> 6;
    const int nloc = lane & 15, g = nloc & 3, hcl = nloc >> 2;
    const int gcol = g * 512 + cs * 16 + wn * 4 + hcl;
    const float b0v = b_ih[gcol] + b_hh[gcol];
    const float b1v = b_ih[2048 + gcol] + b_hh[2048 + gcol];
    const float b0d = b0v + bcomb[gcol];
    const float bofc = b_out[cs * 16 + nloc];

    const ushort* wih0cs = wih0f + (size_t)cs * 65536;
    const ushort* whh0cs = whh0f + (size_t)cs * 65536;
    const ushort* wih1cs = wih1f + (size_t)cs * 65536;
    const ushort* whh1cs = whh1f + (size_t)cs * 65536;
    const ushort* wcombcs = wcombf + (size_t)cs * 65536;
    const ushort* wfOcs = wfOf + (size_t)cs * 16384;

    auto fillW = [&](const ushort* wf) {
        const uint4* s = (const uint4*)wf;
        uint4* d = (uint4*)&sW[0][0][0][0];
        #pragma unroll 1
        for (int i = tid; i < 8192; i += 256) d[i] = s[i];
        __syncthreads();
    };

    float c0[8], c1[8];
    #pragma unroll
    for (int i = 0; i < 8; ++i) { c0[i] = 0.f; c1[i] = 0.f; }
    unsigned ph = 0;
    int cur = 0;

    // ---- encode: 4 chunks x (32 L0 steps, 32 L1 steps), layer-sequential ----
    #pragma unroll 1
    for (int ch = 0; ch < 4; ++ch) {
        fillW(wih0cs);
        #pragma unroll 1
        for (int ti = 0; ti < T; ++ti) {
            int t = ch * T + ti;
            const float* xA = x + ((size_t)xrow0 * SS + t) * 512;
            if (ti == T - 1)
                do_step<true, true, false, true>(xA, (size_t)SS * 512,
                    h0c + (size_t)ti * 32 * 512, nullptr, whh0cs, sW, sA,
                    b0v, c0, h0c + (size_t)(ti + 1) * 32 * 512, h0c,
                    nullptr, 0.f, nullptr, 0, xrow0, lane, wn, cs);
            else
                do_step<true, true, false, false>(xA, (size_t)SS * 512,
                    h0c + (size_t)ti * 32 * 512, nullptr, whh0cs, sW, sA,
                    b0v, c0, h0c + (size_t)(ti + 1) * 32 * 512, nullptr,
                    nullptr, 0.f, nullptr, 0, xrow0, lane, wn, cs);
            xbar(slots, ++ph, cs);
        }
        fillW(wih1cs);
        #pragma unroll 1
        for (int ti = 0; ti < T; ++ti) {
            do_step<false, true, false, false>(
                h0c + (size_t)(ti + 1) * 32 * 512, 512,
                h1r + (size_t)cur * 32 * 512, nullptr, whh1cs, sW, sA,
                b1v, c1, h1r + (size_t)(cur ^ 1) * 32 * 512, nullptr,
                nullptr, 0.f, nullptr, 0, xrow0, lane, wn, cs);
            cur ^= 1;
            xbar(slots, ++ph, cs);
        }
    }

    // ---- decode: per step {L0' + fc} then {L1} ----
    fillW(wcombcs);
    int c0i = 0;      // final h0 carried into h0c slot 0
    #pragma unroll 1
    for (int s = 0; s < NSTEPS; ++s) {
        do_step<false, true, true, false>(
            h1r + (size_t)cur * 32 * 512, 512,
            h0c + (size_t)c0i * 32 * 512, nullptr, whh0cs, sW, sA,
            b0d, c0, h0c + (size_t)(c0i ^ 1) * 32 * 512, nullptr,
            wfOcs, bofc, out, s, xrow0, lane, wn, cs);
        xbar(slots, ++ph, cs);
        c0i ^= 1;
        if (s == NSTEPS - 1) break;
        do_step<false, false, false, false>(
            h0c + (size_t)c0i * 32 * 512, 512,
            h1r + (size_t)cur * 32 * 512, wih1cs, whh1cs, sW, sA,
            b1v, c1, h1r + (size_t)(cur ^ 1) * 32 * 512, nullptr,
            nullptr, 0.f, nullptr, 0, xrow0, lane, wn, cs);
        cur ^= 1;
        xbar(slots, ++ph, cs);
    }
}

// ---------------- host ---------------------------------------------------------
extern "C" void kernel_launch(void* const* d_in, const int* in_sizes, int n_in,
                              void* d_out, int out_size, void* d_ws, size_t ws_size,
                              hipStream_t stream)
{
    const float* x     = (const float*)d_in[0];
    const float* W_ih  = (const float*)d_in[1];
    const float* W_hh  = (const float*)d_in[2];
    const float* b_ih  = (const float*)d_in[3];
    const float* b_hh  = (const float*)d_in[4];
    const float* W_out = (const float*)d_in[5];
    const float* b_out = (const float*)d_in[6];
    float* out = (float*)d_out;
    (void)in_sizes; (void)n_in; (void)out_size; (void)ws_size;

    char* ws = (char*)d_ws;
    unsigned* roster = (unsigned*)(ws + 0);              // 8 ctrs, 64B apart
    unsigned* bar    = (unsigned*)(ws + 512);            // 8 XCDs x 32 slots
    ushort* h0c_all  = (ushort*)(ws + 1536);             // 8*33*32*512*2 = 8,650,752
    ushort* h1_all   = (ushort*)(ws + 1536 + 8650752);   // 8*2*32*512*2  = 524,288
    const size_t ZB  = 1536 + 8650752 + 524288;          // 9,176,576 zeroed
    ushort* wih0f  = (ushort*)(ws + ZB);
    ushort* whh0f  = (ushort*)(ws + ZB + 1 * 4194304);
    ushort* wih1f  = (ushort*)(ws + ZB + 2 * 4194304);
    ushort* whh1f  = (ushort*)(ws + ZB + 3 * 4194304);
    ushort* wcombf = (ushort*)(ws + ZB + 4 * 4194304);
    ushort* wfOf   = (ushort*)(ws + ZB + 5 * 4194304);
    float*  wcomb  = (float*) (ws + ZB + 5 * 4194304 + 1048576);
    float*  bcomb  = (float*) (ws + ZB + 5 * 4194304 + 1048576 + 4194304);
    // total ~35.4 MB

    (void)hipMemsetAsync(d_ws, 0, ZB, stream);
    gemm_wcomb<<<dim3(32, 8), 256, 0, stream>>>(W_ih, W_out, wcomb);
    bcomb_k<<<8, 256, 0, stream>>>(W_ih, b_out, bcomb);
    wsplit5<<<2560, 256, 0, stream>>>(W_ih, W_hh, wcomb,
                                      wih0f, whh0f, wih1f, whh1f, wcombf);
    wsplit_o<<<128, 256, 0, stream>>>(W_out, wfOf);

    persist<<<dim3(256), dim3(256), 0, stream>>>(
        x, wih0f, whh0f, wih1f, whh1f, wcombf, wfOf,
        b_ih, b_hh, b_out, bcomb, h0c_all, h1_all, out, roster, bar);
}

// Round 14
// 5239.533 us; speedup vs baseline: 1.5063x; 1.1271x over previous
//
#include <hip/hip_runtime.h>
#include <math.h>

// TemporalDecoder round 14: R13 + latency pipelining.
// R13 proved the XCD-local design but exposed load latency serially: staging
// chunks load->write with vmcnt(0) 4x per step, and whh fragments load at
// first-use inside the MFMA loop. R14: depth-3 A-register ring (R9's proven
// schedule), B2/wfO register prefetch at step start (1 wave/SIMD -> VGPRs
// free), x pre-converted to f16. Barrier/roster/epilogue unchanged from R13.

#define SS 128
#define NSTEPS 32
#define T 32

typedef __attribute__((ext_vector_type(8))) _Float16 f16x8;
typedef __attribute__((ext_vector_type(4))) float f32x4;

#define LO_SCALE 2048.0f
#define LO_INV   (1.0f / 2048.0f)
#define AGENT __HIP_MEMORY_SCOPE_AGENT

__device__ __forceinline__ uint2 ld_agent_u2(const uint2* p) {
    return __hip_atomic_load(p, __ATOMIC_RELAXED, AGENT);
}

// ---------------- prep kernels ------------------------------------------------
__global__ __launch_bounds__(256) void xcvt(const float* __restrict__ x,
                                            ushort* __restrict__ xh, int n8) {
    int t = blockIdx.x * 256 + threadIdx.x;
    if (t >= n8) return;
    size_t i = (size_t)t * 8;
    float4 a = *(const float4*)(x + i), b = *(const float4*)(x + i + 4);
    union { _Float16 h[8]; uint4 u; } P;
    P.h[0] = (_Float16)a.x; P.h[1] = (_Float16)a.y;
    P.h[2] = (_Float16)a.z; P.h[3] = (_Float16)a.w;
    P.h[4] = (_Float16)b.x; P.h[5] = (_Float16)b.y;
    P.h[6] = (_Float16)b.z; P.h[7] = (_Float16)b.w;
    *(uint4*)(xh + i) = P.u;
}

// layout dst[cs 0..31][wn 0..3][p 0..1][kfg 0..15][lane 0..63][8]
__global__ __launch_bounds__(256) void wsplit5(
    const float* __restrict__ W_ih, const float* __restrict__ W_hh,
    const float* __restrict__ wcomb,
    ushort* __restrict__ wih0, ushort* __restrict__ whh0,
    ushort* __restrict__ wih1, ushort* __restrict__ whh1,
    ushort* __restrict__ wcmb)
{
    int f = blockIdx.x * 256 + threadIdx.x;      // 5 * 131072
    int mat = f >> 17;
    int t = f & 131071;
    int lane = t & 63;
    int kfg = (t >> 6) & 15;
    int wn = (t >> 10) & 3;
    int cs = t >> 12;
    int nloc = lane & 15;
    int g = nloc & 3, hcl = nloc >> 2;
    int n_W = g * 512 + cs * 16 + wn * 4 + hcl;
    int k = kfg * 32 + (lane >> 4) * 8;
    const float* src; ushort* dst;
    const size_t L1OFF = (size_t)2048 * 512;
    switch (mat) {
      case 0: src = W_ih + (size_t)n_W * 512 + k;         dst = wih0; break;
      case 1: src = W_hh + (size_t)n_W * 512 + k;         dst = whh0; break;
      case 2: src = W_ih + L1OFF + (size_t)n_W * 512 + k; dst = wih1; break;
      case 3: src = W_hh + L1OFF + (size_t)n_W * 512 + k; dst = whh1; break;
      default: src = wcomb + (size_t)n_W * 512 + k;       dst = wcmb; break;
    }
    float4 a = *(const float4*)src;
    float4 b = *(const float4*)(src + 4);
    float v[8] = {a.x, a.y, a.z, a.w, b.x, b.y, b.z, b.w};
    union { _Float16 h[8]; uint4 u; } Hi, Lo;
    #pragma unroll
    for (int j = 0; j < 8; ++j) {
        Hi.h[j] = (_Float16)v[j];
        Lo.h[j] = (_Float16)((v[j] - (float)Hi.h[j]) * LO_SCALE);
    }
    size_t b0 = ((((size_t)cs * 4 + wn) * 2 + 0) * 16 + kfg) * 512 + lane * 8;
    size_t b1 = ((((size_t)cs * 4 + wn) * 2 + 1) * 16 + kfg) * 512 + lane * 8;
    *(uint4*)(dst + b0) = Hi.u;
    *(uint4*)(dst + b1) = Lo.u;
}

// Wout frag: [cs][p][kfg][lane][8]; out-col = cs*16 + (lane&15)
__global__ __launch_bounds__(256) void wsplit_o(
    const float* __restrict__ W_out, ushort* __restrict__ wfO)
{
    int f = blockIdx.x * 256 + threadIdx.x;      // 32768
    int lane = f & 63;
    int kfg = (f >> 6) & 15;
    int cs = f >> 10;
    int col = cs * 16 + (lane & 15);
    int k = kfg * 32 + (lane >> 4) * 8;
    const float* src = W_out + (size_t)col * 512 + k;
    float4 a = *(const float4*)src;
    float4 b = *(const float4*)(src + 4);
    float v[8] = {a.x, a.y, a.z, a.w, b.x, b.y, b.z, b.w};
    union { _Float16 h[8]; uint4 u; } Hi, Lo;
    #pragma unroll
    for (int j = 0; j < 8; ++j) {
        Hi.h[j] = (_Float16)v[j];
        Lo.h[j] = (_Float16)((v[j] - (float)Hi.h[j]) * LO_SCALE);
    }
    size_t b0 = (((size_t)cs * 2 + 0) * 16 + kfg) * 512 + lane * 8;
    size_t b1 = (((size_t)cs * 2 + 1) * 16 + kfg) * 512 + lane * 8;
    *(uint4*)(wfO + b0) = Hi.u;
    *(uint4*)(wfO + b1) = Lo.u;
}

// Wcomb = Wih0 @ Wout (fp32)
__global__ __launch_bounds__(256) void gemm_wcomb(
    const float* __restrict__ A, const float* __restrict__ Bm, float* __restrict__ C)
{
    __shared__ float sAf[64][17];
    __shared__ float sBf[16][65];
    const int tid = threadIdx.x;
    const int tx = tid & 15, ty = tid >> 4;
    const int n0 = blockIdx.x * 64, h0 = blockIdx.y * 64;
    float acc[4][4] = {};
    #pragma unroll 1
    for (int k0 = 0; k0 < 512; k0 += 16) {
        __syncthreads();
        {
            int r = tid >> 2, c = (tid & 3) * 4;
            float4 v = *(const float4*)&A[(size_t)(n0 + r) * 512 + k0 + c];
            sAf[r][c] = v.x; sAf[r][c+1] = v.y; sAf[r][c+2] = v.z; sAf[r][c+3] = v.w;
        }
        {
            int r = tid >> 4, c = (tid & 15) * 4;
            float4 v = *(const float4*)&Bm[(size_t)(k0 + r) * 512 + h0 + c];
            sBf[r][c] = v.x; sBf[r][c+1] = v.y; sBf[r][c+2] = v.z; sBf[r][c+3] = v.w;
        }
        __syncthreads();
        #pragma unroll
        for (int kk = 0; kk < 16; ++kk)
            #pragma unroll
            for (int a_ = 0; a_ < 4; ++a_) {
                float av = sAf[ty + 16*a_][kk];
                #pragma unroll
                for (int b_ = 0; b_ < 4; ++b_)
                    acc[a_][b_] += av * sBf[kk][tx + 16*b_];
            }
    }
    #pragma unroll
    for (int a_ = 0; a_ < 4; ++a_)
        #pragma unroll
        for (int b_ = 0; b_ < 4; ++b_)
            C[(size_t)(n0 + ty + 16*a_) * 512 + h0 + tx + 16*b_] = acc[a_][b_];
}

__global__ __launch_bounds__(256) void bcomb_k(const float* __restrict__ Wih0,
                                               const float* __restrict__ bout,
                                               float* __restrict__ bc) {
    int n = blockIdx.x * 256 + threadIdx.x;
    float a = 0.f;
    for (int f = 0; f < 512; ++f) a += Wih0[(size_t)n * 512 + f] * bout[f];
    bc[n] = a;
}

// ---------------- device helpers ---------------------------------------------
__device__ __forceinline__ void wgbar() {
    __builtin_amdgcn_sched_barrier(0);
    asm volatile("s_waitcnt lgkmcnt(0)" ::: "memory");
    __builtin_amdgcn_s_barrier();
    asm volatile("" ::: "memory");
    __builtin_amdgcn_sched_barrier(0);
}

// intra-XCD barrier: per-WG slot store + wave0 scan (R9/R13 proven)
__device__ __forceinline__ void xbar(unsigned* slots, unsigned phase, int cs) {
    __syncthreads();
    if (threadIdx.x == 0)
        __hip_atomic_store(&slots[cs], phase, __ATOMIC_RELAXED, AGENT);
    if (threadIdx.x < 64) {
        unsigned v;
        do {
            v = (threadIdx.x < 32)
                ? __hip_atomic_load(&slots[threadIdx.x], __ATOMIC_RELAXED, AGENT)
                : phase;
        } while (!__all((int)(v >= phase)));
    }
    __syncthreads();
}

// load one 256-k chunk of a 32-row f16 A into regs (coalesced, agent-scope)
__device__ __forceinline__ void ldChunk(uint2 (&u)[8], const ushort* src,
                                        size_t ld, int k0) {
    const int t = threadIdx.x;
    const int row = t >> 3;
    const int cg0 = (t & 7) * 4;
    const ushort* s = src + (size_t)row * ld + k0 + cg0 * 8;
    #pragma unroll
    for (int q = 0; q < 4; ++q) {
        u[2*q]   = ld_agent_u2((const uint2*)(s + q * 8));
        u[2*q+1] = ld_agent_u2((const uint2*)(s + q * 8) + 1);
    }
}
__device__ __forceinline__ void wrChunk(const uint2 (&u)[8], ushort (*sAb)[256]) {
    const int t = threadIdx.x;
    const int row = t >> 3;
    const int cg0 = (t & 7) * 4;
    #pragma unroll
    for (int q = 0; q < 4; ++q) {
        int cg = cg0 + q;
        int slot = (cg & 24) | ((cg ^ row) & 7);
        uint4 wv; wv.x = u[2*q].x; wv.y = u[2*q].y;
        wv.z = u[2*q+1].x; wv.w = u[2*q+1].y;
        *(uint4*)&sAb[row][slot * 8] = wv;
    }
}

// ---------------- the unified LSTM/fc step ------------------------------------
// gates = bias + B1(K=512)@A1 + B2(K=512)@A2 ; cell ; optional fc from A1(=h1)
template<bool B1LDS, bool FC, bool CARRY>
static __device__ __forceinline__ void do_step(
    const ushort* A1, size_t ld1, const ushort* A2,
    const ushort* B1s, const ushort* B2s,
    ushort (*sW)[2][16][512], ushort (*sA)[32][256],
    float* cReg, float biasv, ushort* Hout, ushort* Hcarry,
    const ushort* wfO_cs, float bofc, float* outp, int s, int xrow0,
    int lane, int wn, int cs)
{
    const int lr = lane & 15, lq = lane >> 4;

    // ---- register prefetch of streamed B2 (and fc W) — hidden under chunks 0-1
    f16x8 p2h[16], p2l[16];
    #pragma unroll
    for (int kfg = 0; kfg < 16; ++kfg) {
        p2h[kfg] = *(const f16x8*)(B2s + (((size_t)wn*2+0)*16 + kfg)*512 + lane*8);
        p2l[kfg] = *(const f16x8*)(B2s + (((size_t)wn*2+1)*16 + kfg)*512 + lane*8);
    }
    f16x8 poh[16], pol[16];
    if constexpr (FC) {
        if (wn < 2) {
            #pragma unroll
            for (int kfg = 0; kfg < 16; ++kfg) {
                poh[kfg] = *(const f16x8*)(wfO_cs + ((size_t)0*16 + kfg)*512 + lane*8);
                pol[kfg] = *(const f16x8*)(wfO_cs + ((size_t)1*16 + kfg)*512 + lane*8);
            }
        }
    }

    f32x4 acch[2], accl[2], fch, fcl;
    #pragma unroll
    for (int m = 0; m < 2; ++m) {
        acch[m] = (f32x4){biasv, biasv, biasv, biasv};
        accl[m] = (f32x4){0.f, 0.f, 0.f, 0.f};
    }
    if constexpr (FC) {
        fch = (f32x4){bofc, bofc, bofc, bofc};
        fcl = (f32x4){0.f, 0.f, 0.f, 0.f};
    }

    // ---- depth-3 A register ring (chunks: 0,1 from A1; 2,3 from A2)
    uint2 ur[3][8];
    auto ldc = [&](int c) {
        const ushort* src = (c < 2) ? A1 : A2;
        size_t ld = (c < 2) ? ld1 : (size_t)512;
        ldChunk(ur[c % 3], src, ld, (c & 1) * 256);
    };
    ldc(0); ldc(1); ldc(2);
    wrChunk(ur[0], sA[0]);

    #pragma unroll
    for (int c = 0; c < 4; ++c) {
        wgbar();                          // sA[c&1] ready; ring loads in flight
        if (c + 3 < 4) ldc(c + 3);
        if (c + 1 < 4) wrChunk(ur[(c + 1) % 3], sA[(c + 1) & 1]);
        const int bufc = c & 1;
        #pragma unroll
        for (int kf = 0; kf < 8; ++kf) {
            const int kfg = (c & 1) * 8 + kf;
            f16x8 bh, bl;
            if (c < 2) {
                if constexpr (B1LDS) {
                    bh = *(const f16x8*)&sW[wn][0][kfg][lane * 8];
                    bl = *(const f16x8*)&sW[wn][1][kfg][lane * 8];
                } else {
                    bh = *(const f16x8*)(B1s + (((size_t)wn*2+0)*16 + kfg)*512 + lane*8);
                    bl = *(const f16x8*)(B1s + (((size_t)wn*2+1)*16 + kfg)*512 + lane*8);
                }
            } else {
                bh = p2h[kfg]; bl = p2l[kfg];
            }
            #pragma unroll
            for (int m = 0; m < 2; ++m) {
                int row = m * 16 + lr;
                int cg = kf * 4 + lq;
                int slot = (cg & 24) | ((cg ^ row) & 7);
                f16x8 a = *(const f16x8*)(&sA[bufc][row][0] + slot * 8);
                acch[m] = __builtin_amdgcn_mfma_f32_16x16x32_f16(a, bh, acch[m], 0, 0, 0);
                accl[m] = __builtin_amdgcn_mfma_f32_16x16x32_f16(a, bl, accl[m], 0, 0, 0);
            }
            if constexpr (FC) {
                if (wn < 2 && c < 2) {
                    int row = wn * 16 + lr;
                    int cg = kf * 4 + lq;
                    int slot = (cg & 24) | ((cg ^ row) & 7);
                    f16x8 a = *(const f16x8*)(&sA[bufc][row][0] + slot * 8);
                    fch = __builtin_amdgcn_mfma_f32_16x16x32_f16(a, poh[kfg], fch, 0, 0, 0);
                    fcl = __builtin_amdgcn_mfma_f32_16x16x32_f16(a, pol[kfg], fcl, 0, 0, 0);
                }
            }
        }
    }

    // cell epilogue (unchanged from R13)
    const int nloc = lane & 15;
    const int g = nloc & 3;
    const int colb = cs * 16 + wn * 4;
    #pragma unroll
    for (int m = 0; m < 2; ++m) {
        #pragma unroll
        for (int j = 0; j < 4; ++j) {
            float v = acch[m][j] + accl[m][j] * LO_INV;
            float s1 = __shfl_xor(v, 1, 64);
            float s2 = __shfl_xor(v, 2, 64);
            float s3 = __shfl_xor(v, 3, 64);
            float sel0 = v;
            auto selk = [&](int k) { return (k==0)?sel0:(k==1)?s1:(k==2)?s2:s3; };
            float pi = selk(g), pf = selk(g ^ 1), pg = selk(g ^ 2), po = selk(g ^ 3);
            float ig = 1.f / (1.f + __expf(-pi));
            float fg = 1.f / (1.f + __expf(-pf));
            float e2g = __expf(2.f * fminf(fmaxf(pg, -20.f), 20.f));
            float gg = (e2g - 1.f) / (e2g + 1.f);
            float og = 1.f / (1.f + __expf(-po));
            float cn = fg * cReg[m * 4 + j] + ig * gg;
            cReg[m * 4 + j] = cn;
            float e2c = __expf(2.f * fminf(fmaxf(cn, -20.f), 20.f));
            float th = (e2c - 1.f) / (e2c + 1.f);
            float hn = og * th;
            union { _Float16 h; ushort u; } P; P.h = (_Float16)hn;
            int hb = (int)P.u;
            int base = lane & ~15;
            int b1 = __shfl(hb, base + 4, 64);
            int b2 = __shfl(hb, base + 8, 64);
            int b3 = __shfl(hb, base + 12, 64);
            if (lr == 0) {
                unsigned long long pk =
                    (unsigned long long)(unsigned)(hb & 0xFFFF)
                    | ((unsigned long long)(unsigned)(b1 & 0xFFFF) << 16)
                    | ((unsigned long long)(unsigned)(b2 & 0xFFFF) << 32)
                    | ((unsigned long long)(unsigned)(b3 & 0xFFFF) << 48);
                int row = m * 16 + lq * 4 + j;
                *(unsigned long long*)&Hout[(size_t)row * 512 + colb] = pk;
                if constexpr (CARRY)
                    *(unsigned long long*)&Hcarry[(size_t)row * 512 + colb] = pk;
            }
        }
    }
    if constexpr (FC) {
        if (wn < 2) {
            #pragma unroll
            for (int j = 0; j < 4; ++j) {
                float v = fch[j] + fcl[j] * LO_INV;
                int row = wn * 16 + lq * 4 + j;
                outp[((size_t)(xrow0 + row) * NSTEPS + s) * 512 + cs * 16 + lr] = v;
            }
        }
    }
}

// ---------------- persistent kernel ------------------------------------------
__global__ __launch_bounds__(256, 1) void persist(
    const ushort* __restrict__ xh,
    const ushort* __restrict__ wih0f, const ushort* __restrict__ whh0f,
    const ushort* __restrict__ wih1f, const ushort* __restrict__ whh1f,
    const ushort* __restrict__ wcombf, const ushort* __restrict__ wfOf,
    const float* __restrict__ b_ih, const float* __restrict__ b_hh,
    const float* __restrict__ b_out, const float* __restrict__ bcomb,
    ushort* h0c_all, ushort* h1_all,
    float* out, unsigned* roster, unsigned* bar)
{
    __shared__ ushort sW[4][2][16][512];      // 128KB
    __shared__ ushort sA[2][32][256];         // 32KB

    const int tid = threadIdx.x;
    if (tid == 0) {
        int xid;
        asm volatile("s_getreg_b32 %0, hwreg(HW_REG_XCC_ID)" : "=s"(xid));
        xid &= 7;
        unsigned slot = atomicAdd(&roster[xid * 16], 1u) & 31u;
        *(int*)&sA[0][0][0] = xid * 32 + (int)slot;
    }
    __syncthreads();
    const int packed = *(const int*)&sA[0][0][0];
    __syncthreads();
    const int xcd = packed >> 5, cs = packed & 31;
    const int xrow0 = xcd * 32;

    ushort* h0c = h0c_all + (size_t)xcd * 33 * 32 * 512;
    ushort* h1r = h1_all + (size_t)xcd * 2 * 32 * 512;
    unsigned* slots = bar + xcd * 32;

    const int lane = tid & 63, wn = tid >> 6;
    const int nloc = lane & 15, g = nloc & 3, hcl = nloc >> 2;
    const int gcol = g * 512 + cs * 16 + wn * 4 + hcl;
    const float b0v = b_ih[gcol] + b_hh[gcol];
    const float b1v = b_ih[2048 + gcol] + b_hh[2048 + gcol];
    const float b0d = b0v + bcomb[gcol];
    const float bofc = b_out[cs * 16 + nloc];

    const ushort* wih0cs = wih0f + (size_t)cs * 65536;
    const ushort* whh0cs = whh0f + (size_t)cs * 65536;
    const ushort* wih1cs = wih1f + (size_t)cs * 65536;
    const ushort* whh1cs = whh1f + (size_t)cs * 65536;
    const ushort* wcombcs = wcombf + (size_t)cs * 65536;
    const ushort* wfOcs = wfOf + (size_t)cs * 16384;

    auto fillW = [&](const ushort* wf) {
        const uint4* s = (const uint4*)wf;
        uint4* d = (uint4*)&sW[0][0][0][0];
        #pragma unroll 1
        for (int i = tid; i < 8192; i += 256) d[i] = s[i];
        __syncthreads();
    };

    float c0[8], c1[8];
    #pragma unroll
    for (int i = 0; i < 8; ++i) { c0[i] = 0.f; c1[i] = 0.f; }
    unsigned ph = 0;
    int cur = 0;

    // ---- encode: 4 chunks x (32 L0 steps, 32 L1 steps), layer-sequential ----
    #pragma unroll 1
    for (int ch = 0; ch < 4; ++ch) {
        fillW(wih0cs);
        #pragma unroll 1
        for (int ti = 0; ti < T; ++ti) {
            int t = ch * T + ti;
            const ushort* xA = xh + ((size_t)xrow0 * SS + t) * 512;
            if (ti == T - 1)
                do_step<true, false, true>(xA, (size_t)SS * 512,
                    h0c + (size_t)ti * 32 * 512, nullptr, whh0cs, sW, sA,
                    c0, b0v, h0c + (size_t)(ti + 1) * 32 * 512, h0c,
                    nullptr, 0.f, nullptr, 0, xrow0, lane, wn, cs);
            else
                do_step<true, false, false>(xA, (size_t)SS * 512,
                    h0c + (size_t)ti * 32 * 512, nullptr, whh0cs, sW, sA,
                    c0, b0v, h0c + (size_t)(ti + 1) * 32 * 512, nullptr,
                    nullptr, 0.f, nullptr, 0, xrow0, lane, wn, cs);
            xbar(slots, ++ph, cs);
        }
        fillW(wih1cs);
        #pragma unroll 1
        for (int ti = 0; ti < T; ++ti) {
            do_step<true, false, false>(
                h0c + (size_t)(ti + 1) * 32 * 512, 512,
                h1r + (size_t)cur * 32 * 512, nullptr, whh1cs, sW, sA,
                c1, b1v, h1r + (size_t)(cur ^ 1) * 32 * 512, nullptr,
                nullptr, 0.f, nullptr, 0, xrow0, lane, wn, cs);
            cur ^= 1;
            xbar(slots, ++ph, cs);
        }
    }

    // ---- decode: per step {L0' + fc} then {L1} ----
    fillW(wcombcs);
    int c0i = 0;
    #pragma unroll 1
    for (int s = 0; s < NSTEPS; ++s) {
        do_step<true, true, false>(
            h1r + (size_t)cur * 32 * 512, 512,
            h0c + (size_t)c0i * 32 * 512, nullptr, whh0cs, sW, sA,
            c0, b0d, h0c + (size_t)(c0i ^ 1) * 32 * 512, nullptr,
            wfOcs, bofc, out, s, xrow0, lane, wn, cs);
        xbar(slots, ++ph, cs);
        c0i ^= 1;
        if (s == NSTEPS - 1) break;
        do_step<false, false, false>(
            h0c + (size_t)c0i * 32 * 512, 512,
            h1r + (size_t)cur * 32 * 512, wih1cs, whh1cs, sW, sA,
            c1, b1v, h1r + (size_t)(cur ^ 1) * 32 * 512, nullptr,
            nullptr, 0.f, nullptr, 0, xrow0, lane, wn, cs);
        cur ^= 1;
        xbar(slots, ++ph, cs);
    }
}

// ---------------- host ---------------------------------------------------------
extern "C" void kernel_launch(void* const* d_in, const int* in_sizes, int n_in,
                              void* d_out, int out_size, void* d_ws, size_t ws_size,
                              hipStream_t stream)
{
    const float* x     = (const float*)d_in[0];
    const float* W_ih  = (const float*)d_in[1];
    const float* W_hh  = (const float*)d_in[2];
    const float* b_ih  = (const float*)d_in[3];
    const float* b_hh  = (const float*)d_in[4];
    const float* W_out = (const float*)d_in[5];
    const float* b_out = (const float*)d_in[6];
    float* out = (float*)d_out;
    (void)n_in; (void)out_size; (void)ws_size;

    char* ws = (char*)d_ws;
    unsigned* roster = (unsigned*)(ws + 0);              // 8 ctrs, 64B apart
    unsigned* bar    = (unsigned*)(ws + 512);            // 8 XCDs x 32 slots
    ushort* h0c_all  = (ushort*)(ws + 8192);             // 8*33*32*512*2 = 8,650,752
    ushort* h1_all   = (ushort*)(ws + 8192 + 8650752);   // 8*2*32*512*2  = 524,288
    const size_t ZB  = 8192 + 8650752 + 524288;          // 9,183,232 zeroed
    ushort* wih0f  = (ushort*)(ws + ZB);
    ushort* whh0f  = (ushort*)(ws + ZB + 1 * 4194304);
    ushort* wih1f  = (ushort*)(ws + ZB + 2 * 4194304);
    ushort* whh1f  = (ushort*)(ws + ZB + 3 * 4194304);
    ushort* wcombf = (ushort*)(ws + ZB + 4 * 4194304);
    ushort* wfOf   = (ushort*)(ws + ZB + 5 * 4194304);                 // 1MB
    float*  wcomb  = (float*) (ws + ZB + 5 * 4194304 + 1048576);       // 4MB
    float*  bcomb  = (float*) (ws + ZB + 5 * 4194304 + 1048576 + 4194304);  // 8KB
    ushort* xh     = (ushort*)(ws + ZB + 5 * 4194304 + 1048576 + 4194304 + 65536);
    // xh = 33.5MB; total ~68 MB

    (void)hipMemsetAsync(d_ws, 0, ZB, stream);
    {
        int n8 = (in_sizes[0] + 7) / 8;                  // 2,097,152
        int blocks = (n8 + 255) / 256;                   // 8192
        xcvt<<<blocks, 256, 0, stream>>>(x, xh, n8);
    }
    gemm_wcomb<<<dim3(32, 8), 256, 0, stream>>>(W_ih, W_out, wcomb);
    bcomb_k<<<8, 256, 0, stream>>>(W_ih, b_out, bcomb);
    wsplit5<<<2560, 256, 0, stream>>>(W_ih, W_hh, wcomb,
                                      wih0f, whh0f, wih1f, whh1f, wcombf);
    wsplit_o<<<128, 256, 0, stream>>>(W_out, wfOf);

    persist<<<dim3(256), dim3(256), 0, stream>>>(
        xh, wih0f, whh0f, wih1f, whh1f, wcombf, wfOf,
        b_ih, b_hh, b_out, bcomb, h0c_all, h1_all, out, roster, bar);
}

// Round 15
// 3951.087 us; speedup vs baseline: 1.9976x; 1.3261x over previous
//
#include <hip/hip_runtime.h>
#include <math.h>

// TemporalDecoder round 15: f16-hi-ONLY weights -> wih+whh both LDS-resident
// (128KB/CU) during encode: zero per-phase weight streaming (R14's 4MB/XCD
// whh stream was the 6.8MB/phase FETCH + ~3us/phase floor), and MFMA count
// halves. Decode: phase-B weights LDS-resident (filled once); phase-A streams
// wcomb/whh0/wfO-hi to regs, A-loads issued FIRST (vmcnt order fix), B2
// prefetch deferred to c==1. Numerics experiment: f16 weight quantization
// ~2^-12 -> predicted final error 5e-4..1.5e-3 vs threshold 2.37e-3.

#define SS 128
#define NSTEPS 32
#define T 32

typedef __attribute__((ext_vector_type(8))) _Float16 f16x8;
typedef __attribute__((ext_vector_type(4))) float f32x4;

#define AGENT __HIP_MEMORY_SCOPE_AGENT

__device__ __forceinline__ uint2 ld_agent_u2(const uint2* p) {
    return __hip_atomic_load(p, __ATOMIC_RELAXED, AGENT);
}

// ---------------- prep kernels ------------------------------------------------
__global__ __launch_bounds__(256) void xcvt(const float* __restrict__ x,
                                            ushort* __restrict__ xh, int n8) {
    int t = blockIdx.x * 256 + threadIdx.x;
    if (t >= n8) return;
    size_t i = (size_t)t * 8;
    float4 a = *(const float4*)(x + i), b = *(const float4*)(x + i + 4);
    union { _Float16 h[8]; uint4 u; } P;
    P.h[0] = (_Float16)a.x; P.h[1] = (_Float16)a.y;
    P.h[2] = (_Float16)a.z; P.h[3] = (_Float16)a.w;
    P.h[4] = (_Float16)b.x; P.h[5] = (_Float16)b.y;
    P.h[6] = (_Float16)b.z; P.h[7] = (_Float16)b.w;
    *(uint4*)(xh + i) = P.u;
}

// frag-split 5 K=512 matrices, f16-hi only.
// layout dst[cs 0..31][wn 0..3][kfg 0..15][lane 0..63][8]  (64KB per cs-slice)
__global__ __launch_bounds__(256) void wsplit5(
    const float* __restrict__ W_ih, const float* __restrict__ W_hh,
    const float* __restrict__ wcomb,
    ushort* __restrict__ wih0, ushort* __restrict__ whh0,
    ushort* __restrict__ wih1, ushort* __restrict__ whh1,
    ushort* __restrict__ wcmb)
{
    int f = blockIdx.x * 256 + threadIdx.x;      // 5 * 131072
    int mat = f >> 17;
    int t = f & 131071;
    int lane = t & 63;
    int kfg = (t >> 6) & 15;
    int wn = (t >> 10) & 3;
    int cs = t >> 12;
    int nloc = lane & 15;
    int g = nloc & 3, hcl = nloc >> 2;
    int n_W = g * 512 + cs * 16 + wn * 4 + hcl;
    int k = kfg * 32 + (lane >> 4) * 8;
    const float* src; ushort* dst;
    const size_t L1OFF = (size_t)2048 * 512;
    switch (mat) {
      case 0: src = W_ih + (size_t)n_W * 512 + k;         dst = wih0; break;
      case 1: src = W_hh + (size_t)n_W * 512 + k;         dst = whh0; break;
      case 2: src = W_ih + L1OFF + (size_t)n_W * 512 + k; dst = wih1; break;
      case 3: src = W_hh + L1OFF + (size_t)n_W * 512 + k; dst = whh1; break;
      default: src = wcomb + (size_t)n_W * 512 + k;       dst = wcmb; break;
    }
    float4 a = *(const float4*)src;
    float4 b = *(const float4*)(src + 4);
    float v[8] = {a.x, a.y, a.z, a.w, b.x, b.y, b.z, b.w};
    union { _Float16 h[8]; uint4 u; } Hi;
    #pragma unroll
    for (int j = 0; j < 8; ++j) Hi.h[j] = (_Float16)v[j];
    size_t b0 = (((size_t)cs * 4 + wn) * 16 + kfg) * 512 + lane * 8;
    *(uint4*)(dst + b0) = Hi.u;
}

// Wout frag hi-only: [cs][kfg][lane][8]; out-col = cs*16 + (lane&15)
__global__ __launch_bounds__(256) void wsplit_o(
    const float* __restrict__ W_out, ushort* __restrict__ wfO)
{
    int f = blockIdx.x * 256 + threadIdx.x;      // 32768
    int lane = f & 63;
    int kfg = (f >> 6) & 15;
    int cs = f >> 10;
    int col = cs * 16 + (lane & 15);
    int k = kfg * 32 + (lane >> 4) * 8;
    const float* src = W_out + (size_t)col * 512 + k;
    float4 a = *(const float4*)src;
    float4 b = *(const float4*)(src + 4);
    float v[8] = {a.x, a.y, a.z, a.w, b.x, b.y, b.z, b.w};
    union { _Float16 h[8]; uint4 u; } Hi;
    #pragma unroll
    for (int j = 0; j < 8; ++j) Hi.h[j] = (_Float16)v[j];
    size_t b0 = ((size_t)cs * 16 + kfg) * 512 + lane * 8;
    *(uint4*)(wfO + b0) = Hi.u;
}

// Wcomb = Wih0 @ Wout (fp32)
__global__ __launch_bounds__(256) void gemm_wcomb(
    const float* __restrict__ A, const float* __restrict__ Bm, float* __restrict__ C)
{
    __shared__ float sAf[64][17];
    __shared__ float sBf[16][65];
    const int tid = threadIdx.x;
    const int tx = tid & 15, ty = tid >> 4;
    const int n0 = blockIdx.x * 64, h0 = blockIdx.y * 64;
    float acc[4][4] = {};
    #pragma unroll 1
    for (int k0 = 0; k0 < 512; k0 += 16) {
        __syncthreads();
        {
            int r = tid >> 2, c = (tid & 3) * 4;
            float4 v = *(const float4*)&A[(size_t)(n0 + r) * 512 + k0 + c];
            sAf[r][c] = v.x; sAf[r][c+1] = v.y; sAf[r][c+2] = v.z; sAf[r][c+3] = v.w;
        }
        {
            int r = tid >> 4, c = (tid & 15) * 4;
            float4 v = *(const float4*)&Bm[(size_t)(k0 + r) * 512 + h0 + c];
            sBf[r][c] = v.x; sBf[r][c+1] = v.y; sBf[r][c+2] = v.z; sBf[r][c+3] = v.w;
        }
        __syncthreads();
        #pragma unroll
        for (int kk = 0; kk < 16; ++kk)
            #pragma unroll
            for (int a_ = 0; a_ < 4; ++a_) {
                float av = sAf[ty + 16*a_][kk];
                #pragma unroll
                for (int b_ = 0; b_ < 4; ++b_)
                    acc[a_][b_] += av * sBf[kk][tx + 16*b_];
            }
    }
    #pragma unroll
    for (int a_ = 0; a_ < 4; ++a_)
        #pragma unroll
        for (int b_ = 0; b_ < 4; ++b_)
            C[(size_t)(n0 + ty + 16*a_) * 512 + h0 + tx + 16*b_] = acc[a_][b_];
}

__global__ __launch_bounds__(256) void bcomb_k(const float* __restrict__ Wih0,
                                               const float* __restrict__ bout,
                                               float* __restrict__ bc) {
    int n = blockIdx.x * 256 + threadIdx.x;
    float a = 0.f;
    for (int f = 0; f < 512; ++f) a += Wih0[(size_t)n * 512 + f] * bout[f];
    bc[n] = a;
}

// ---------------- device helpers ---------------------------------------------
__device__ __forceinline__ void wgbar() {
    __builtin_amdgcn_sched_barrier(0);
    asm volatile("s_waitcnt lgkmcnt(0)" ::: "memory");
    __builtin_amdgcn_s_barrier();
    asm volatile("" ::: "memory");
    __builtin_amdgcn_sched_barrier(0);
}

// intra-XCD barrier: per-WG slot store + wave0 scan (R9/R13 proven)
__device__ __forceinline__ void xbar(unsigned* slots, unsigned phase, int cs) {
    __syncthreads();
    if (threadIdx.x == 0)
        __hip_atomic_store(&slots[cs], phase, __ATOMIC_RELAXED, AGENT);
    if (threadIdx.x < 64) {
        unsigned v;
        do {
            v = (threadIdx.x < 32)
                ? __hip_atomic_load(&slots[threadIdx.x], __ATOMIC_RELAXED, AGENT)
                : phase;
        } while (!__all((int)(v >= phase)));
    }
    __syncthreads();
}

// load one 256-k chunk of a 32-row f16 A into regs (coalesced, agent-scope)
__device__ __forceinline__ void ldChunk(uint2 (&u)[8], const ushort* src,
                                        size_t ld, int k0) {
    const int t = threadIdx.x;
    const int row = t >> 3;
    const int cg0 = (t & 7) * 4;
    const ushort* s = src + (size_t)row * ld + k0 + cg0 * 8;
    #pragma unroll
    for (int q = 0; q < 4; ++q) {
        u[2*q]   = ld_agent_u2((const uint2*)(s + q * 8));
        u[2*q+1] = ld_agent_u2((const uint2*)(s + q * 8) + 1);
    }
}
__device__ __forceinline__ void wrChunk(const uint2 (&u)[8], ushort (*sAb)[256]) {
    const int t = threadIdx.x;
    const int row = t >> 3;
    const int cg0 = (t & 7) * 4;
    #pragma unroll
    for (int q = 0; q < 4; ++q) {
        int cg = cg0 + q;
        int slot = (cg & 24) | ((cg ^ row) & 7);
        uint4 wv; wv.x = u[2*q].x; wv.y = u[2*q].y;
        wv.z = u[2*q+1].x; wv.w = u[2*q+1].y;
        *(uint4*)&sAb[row][slot * 8] = wv;
    }
}

// ---------------- the unified LSTM/fc step ------------------------------------
// gates = bias + B1(K=512)@A1 + B2(K=512)@A2 ; cell ; optional fc from A1(=h1)
// BLDS: B1=sW[0], B2=sW[1] (LDS-resident). else B1/B2 streamed to regs.
template<bool BLDS, bool FC, bool CARRY>
static __device__ __forceinline__ void do_step(
    const ushort* A1, size_t ld1, const ushort* A2,
    const ushort* B1s, const ushort* B2s,
    ushort (*sW)[4][16][512], ushort (*sA)[32][256],
    float* cReg, float biasv, ushort* Hout, ushort* Hcarry,
    const ushort* wfO_cs, float bofc, float* outp, int s, int xrow0,
    int lane, int wn, int cs)
{
    const int lr = lane & 15, lq = lane >> 4;

    // ---- depth-3 A register ring, issued FIRST (chunks: 0,1 from A1; 2,3 A2)
    uint2 ur[3][8];
    auto ldc = [&](int c) {
        const ushort* src = (c < 2) ? A1 : A2;
        size_t ld = (c < 2) ? ld1 : (size_t)512;
        ldChunk(ur[c % 3], src, ld, (c & 1) * 256);
    };
    ldc(0); ldc(1); ldc(2);

    // ---- streamed-B prefetch (decode-A only): B1 + fc now, B2 deferred to c==1
    f16x8 pb1[16], pb2[16], po[16];
    if constexpr (!BLDS) {
        #pragma unroll
        for (int kfg = 0; kfg < 16; ++kfg)
            pb1[kfg] = *(const f16x8*)(B1s + (((size_t)wn) * 16 + kfg) * 512 + lane * 8);
    }
    if constexpr (FC) {
        if (wn < 2) {
            #pragma unroll
            for (int kfg = 0; kfg < 16; ++kfg)
                po[kfg] = *(const f16x8*)(wfO_cs + (size_t)kfg * 512 + lane * 8);
        }
    }

    f32x4 acch[2], fch;
    #pragma unroll
    for (int m = 0; m < 2; ++m) acch[m] = (f32x4){biasv, biasv, biasv, biasv};
    if constexpr (FC) fch = (f32x4){bofc, bofc, bofc, bofc};

    wrChunk(ur[0], sA[0]);

    #pragma unroll
    for (int c = 0; c < 4; ++c) {
        wgbar();                          // sA[c&1] ready; ring loads in flight
        if constexpr (!BLDS) {
            if (c == 1) {                 // B2 prefetch under c=1 compute
                #pragma unroll
                for (int kfg = 0; kfg < 16; ++kfg)
                    pb2[kfg] = *(const f16x8*)(B2s + (((size_t)wn) * 16 + kfg) * 512 + lane * 8);
            }
        }
        if (c + 3 < 4) ldc(c + 3);
        if (c + 1 < 4) wrChunk(ur[(c + 1) % 3], sA[(c + 1) & 1]);
        const int bufc = c & 1;
        #pragma unroll
        for (int kf = 0; kf < 8; ++kf) {
            const int kfg = (c & 1) * 8 + kf;
            f16x8 bh;
            if constexpr (BLDS) {
                bh = *(const f16x8*)&sW[(c < 2) ? 0 : 1][wn][kfg][lane * 8];
            } else {
                bh = (c < 2) ? pb1[kfg] : pb2[kfg];
            }
            #pragma unroll
            for (int m = 0; m < 2; ++m) {
                int row = m * 16 + lr;
                int cg = kf * 4 + lq;
                int slot = (cg & 24) | ((cg ^ row) & 7);
                f16x8 a = *(const f16x8*)(&sA[bufc][row][0] + slot * 8);
                acch[m] = __builtin_amdgcn_mfma_f32_16x16x32_f16(a, bh, acch[m], 0, 0, 0);
            }
            if constexpr (FC) {
                if (wn < 2 && c < 2) {
                    int row = wn * 16 + lr;
                    int cg = kf * 4 + lq;
                    int slot = (cg & 24) | ((cg ^ row) & 7);
                    f16x8 a = *(const f16x8*)(&sA[bufc][row][0] + slot * 8);
                    fch = __builtin_amdgcn_mfma_f32_16x16x32_f16(a, po[kfg], fch, 0, 0, 0);
                }
            }
        }
    }

    // cell epilogue
    const int nloc = lane & 15;
    const int g = nloc & 3;
    const int colb = cs * 16 + wn * 4;
    #pragma unroll
    for (int m = 0; m < 2; ++m) {
        #pragma unroll
        for (int j = 0; j < 4; ++j) {
            float v = acch[m][j];
            float s1 = __shfl_xor(v, 1, 64);
            float s2 = __shfl_xor(v, 2, 64);
            float s3 = __shfl_xor(v, 3, 64);
            float sel0 = v;
            auto selk = [&](int k) { return (k==0)?sel0:(k==1)?s1:(k==2)?s2:s3; };
            float pi = selk(g), pf = selk(g ^ 1), pg = selk(g ^ 2), po_ = selk(g ^ 3);
            float ig = 1.f / (1.f + __expf(-pi));
            float fg = 1.f / (1.f + __expf(-pf));
            float e2g = __expf(2.f * fminf(fmaxf(pg, -20.f), 20.f));
            float gg = (e2g - 1.f) / (e2g + 1.f);
            float og = 1.f / (1.f + __expf(-po_));
            float cn = fg * cReg[m * 4 + j] + ig * gg;
            cReg[m * 4 + j] = cn;
            float e2c = __expf(2.f * fminf(fmaxf(cn, -20.f), 20.f));
            float th = (e2c - 1.f) / (e2c + 1.f);
            float hn = og * th;
            union { _Float16 h; ushort u; } P; P.h = (_Float16)hn;
            int hb = (int)P.u;
            int base = lane & ~15;
            int b1 = __shfl(hb, base + 4, 64);
            int b2 = __shfl(hb, base + 8, 64);
            int b3 = __shfl(hb, base + 12, 64);
            if (lr == 0) {
                unsigned long long pk =
                    (unsigned long long)(unsigned)(hb & 0xFFFF)
                    | ((unsigned long long)(unsigned)(b1 & 0xFFFF) << 16)
                    | ((unsigned long long)(unsigned)(b2 & 0xFFFF) << 32)
                    | ((unsigned long long)(unsigned)(b3 & 0xFFFF) << 48);
                int row = m * 16 + lq * 4 + j;
                *(unsigned long long*)&Hout[(size_t)row * 512 + colb] = pk;
                if constexpr (CARRY)
                    *(unsigned long long*)&Hcarry[(size_t)row * 512 + colb] = pk;
            }
        }
    }
    if constexpr (FC) {
        if (wn < 2) {
            #pragma unroll
            for (int j = 0; j < 4; ++j) {
                float v = fch[j];
                int row = wn * 16 + lq * 4 + j;
                outp[((size_t)(xrow0 + row) * NSTEPS + s) * 512 + cs * 16 + lr] = v;
            }
        }
    }
}

// ---------------- persistent kernel ------------------------------------------
__global__ __launch_bounds__(256, 1) void persist(
    const ushort* __restrict__ xh,
    const ushort* __restrict__ wih0f, const ushort* __restrict__ whh0f,
    const ushort* __restrict__ wih1f, const ushort* __restrict__ whh1f,
    const ushort* __restrict__ wcombf, const ushort* __restrict__ wfOf,
    const float* __restrict__ b_ih, const float* __restrict__ b_hh,
    const float* __restrict__ b_out, const float* __restrict__ bcomb,
    ushort* h0c_all, ushort* h1_all,
    float* out, unsigned* roster, unsigned* bar)
{
    __shared__ ushort sW[2][4][16][512];      // 128KB: [mat][wn][kfg][lane*8]
    __shared__ ushort sA[2][32][256];         // 32KB

    const int tid = threadIdx.x;
    if (tid == 0) {
        int xid;
        asm volatile("s_getreg_b32 %0, hwreg(HW_REG_XCC_ID)" : "=s"(xid));
        xid &= 7;
        unsigned slot = atomicAdd(&roster[xid * 16], 1u) & 31u;
        *(int*)&sA[0][0][0] = xid * 32 + (int)slot;
    }
    __syncthreads();
    const int packed = *(const int*)&sA[0][0][0];
    __syncthreads();
    const int xcd = packed >> 5, cs = packed & 31;
    const int xrow0 = xcd * 32;

    ushort* h0c = h0c_all + (size_t)xcd * 33 * 32 * 512;
    ushort* h1r = h1_all + (size_t)xcd * 2 * 32 * 512;
    unsigned* slots = bar + xcd * 32;

    const int lane = tid & 63, wn = tid >> 6;
    const int nloc = lane & 15, g = nloc & 3, hcl = nloc >> 2;
    const int gcol = g * 512 + cs * 16 + wn * 4 + hcl;
    const float b0v = b_ih[gcol] + b_hh[gcol];
    const float b1v = b_ih[2048 + gcol] + b_hh[2048 + gcol];
    const float b0d = b0v + bcomb[gcol];
    const float bofc = b_out[cs * 16 + nloc];

    const ushort* wih0cs = wih0f + (size_t)cs * 32768;
    const ushort* whh0cs = whh0f + (size_t)cs * 32768;
    const ushort* wih1cs = wih1f + (size_t)cs * 32768;
    const ushort* whh1cs = whh1f + (size_t)cs * 32768;
    const ushort* wcombcs = wcombf + (size_t)cs * 32768;
    const ushort* wfOcs = wfOf + (size_t)cs * 8192;

    auto fillW2 = [&](const ushort* w1, const ushort* w2) {
        const uint4* s1 = (const uint4*)w1;
        const uint4* s2 = (const uint4*)w2;
        uint4* d1 = (uint4*)&sW[0][0][0][0];
        uint4* d2 = (uint4*)&sW[1][0][0][0];
        #pragma unroll 1
        for (int i = tid; i < 4096; i += 256) { d1[i] = s1[i]; d2[i] = s2[i]; }
        __syncthreads();
    };

    float c0[8], c1[8];
    #pragma unroll
    for (int i = 0; i < 8; ++i) { c0[i] = 0.f; c1[i] = 0.f; }
    unsigned ph = 0;
    int cur = 0;

    // ---- encode: 4 chunks x (32 L0 steps, 32 L1 steps), layer-sequential ----
    #pragma unroll 1
    for (int ch = 0; ch < 4; ++ch) {
        fillW2(wih0cs, whh0cs);
        #pragma unroll 1
        for (int ti = 0; ti < T; ++ti) {
            int t = ch * T + ti;
            const ushort* xA = xh + ((size_t)xrow0 * SS + t) * 512;
            if (ti == T - 1)
                do_step<true, false, true>(xA, (size_t)SS * 512,
                    h0c + (size_t)ti * 32 * 512, nullptr, nullptr, sW, sA,
                    c0, b0v, h0c + (size_t)(ti + 1) * 32 * 512, h0c,
                    nullptr, 0.f, nullptr, 0, xrow0, lane, wn, cs);
            else
                do_step<true, false, false>(xA, (size_t)SS * 512,
                    h0c + (size_t)ti * 32 * 512, nullptr, nullptr, sW, sA,
                    c0, b0v, h0c + (size_t)(ti + 1) * 32 * 512, nullptr,
                    nullptr, 0.f, nullptr, 0, xrow0, lane, wn, cs);
            xbar(slots, ++ph, cs);
        }
        fillW2(wih1cs, whh1cs);
        #pragma unroll 1
        for (int ti = 0; ti < T; ++ti) {
            do_step<true, false, false>(
                h0c + (size_t)(ti + 1) * 32 * 512, 512,
                h1r + (size_t)cur * 32 * 512, nullptr, nullptr, sW, sA,
                c1, b1v, h1r + (size_t)(cur ^ 1) * 32 * 512, nullptr,
                nullptr, 0.f, nullptr, 0, xrow0, lane, wn, cs);
            cur ^= 1;
            xbar(slots, ++ph, cs);
        }
    }

    // ---- decode: phase A {L0'+fc, streamed B}; phase B {L1, LDS-resident} ----
    fillW2(wih1cs, whh1cs);       // L1 weights stay resident all decode
    int c0i = 0;
    #pragma unroll 1
    for (int s = 0; s < NSTEPS; ++s) {
        do_step<false, true, false>(
            h1r + (size_t)cur * 32 * 512, 512,
            h0c + (size_t)c0i * 32 * 512, wcombcs, whh0cs, sW, sA,
            c0, b0d, h0c + (size_t)(c0i ^ 1) * 32 * 512, nullptr,
            wfOcs, bofc, out, s, xrow0, lane, wn, cs);
        xbar(slots, ++ph, cs);
        c0i ^= 1;
        if (s == NSTEPS - 1) break;
        do_step<true, false, false>(
            h0c + (size_t)c0i * 32 * 512, 512,
            h1r + (size_t)cur * 32 * 512, nullptr, nullptr, sW, sA,
            c1, b1v, h1r + (size_t)(cur ^ 1) * 32 * 512, nullptr,
            nullptr, 0.f, nullptr, 0, xrow0, lane, wn, cs);
        cur ^= 1;
        xbar(slots, ++ph, cs);
    }
}

// ---------------- host ---------------------------------------------------------
extern "C" void kernel_launch(void* const* d_in, const int* in_sizes, int n_in,
                              void* d_out, int out_size, void* d_ws, size_t ws_size,
                              hipStream_t stream)
{
    const float* x     = (const float*)d_in[0];
    const float* W_ih  = (const float*)d_in[1];
    const float* W_hh  = (const float*)d_in[2];
    const float* b_ih  = (const float*)d_in[3];
    const float* b_hh  = (const float*)d_in[4];
    const float* W_out = (const float*)d_in[5];
    const float* b_out = (const float*)d_in[6];
    float* out = (float*)d_out;
    (void)n_in; (void)out_size; (void)ws_size;

    char* ws = (char*)d_ws;
    unsigned* roster = (unsigned*)(ws + 0);              // 8 ctrs, 64B apart
    unsigned* bar    = (unsigned*)(ws + 512);            // 8 XCDs x 32 slots
    ushort* h0c_all  = (ushort*)(ws + 8192);             // 8*33*32*512*2 = 8,650,752
    ushort* h1_all   = (ushort*)(ws + 8192 + 8650752);   // 8*2*32*512*2  = 524,288
    const size_t ZB  = 8192 + 8650752 + 524288;          // 9,183,232 zeroed
    ushort* wih0f  = (ushort*)(ws + ZB + 0 * 2097152);
    ushort* whh0f  = (ushort*)(ws + ZB + 1 * 2097152);
    ushort* wih1f  = (ushort*)(ws + ZB + 2 * 2097152);
    ushort* whh1f  = (ushort*)(ws + ZB + 3 * 2097152);
    ushort* wcombf = (ushort*)(ws + ZB + 4 * 2097152);
    ushort* wfOf   = (ushort*)(ws + ZB + 5 * 2097152);               // 512KB
    float*  wcomb  = (float*) (ws + ZB + 5 * 2097152 + 524288);      // 4MB
    float*  bcomb  = (float*) (ws + ZB + 5 * 2097152 + 524288 + 4194304);
    ushort* xh     = (ushort*)(ws + ZB + 5 * 2097152 + 524288 + 4194304 + 65536);
    // xh = 33.5MB; total ~57 MB

    (void)hipMemsetAsync(d_ws, 0, ZB, stream);
    {
        int n8 = (in_sizes[0] + 7) / 8;                  // 2,097,152
        int blocks = (n8 + 255) / 256;                   // 8192
        xcvt<<<blocks, 256, 0, stream>>>(x, xh, n8);
    }
    gemm_wcomb<<<dim3(32, 8), 256, 0, stream>>>(W_ih, W_out, wcomb);
    bcomb_k<<<8, 256, 0, stream>>>(W_ih, b_out, bcomb);
    wsplit5<<<2560, 256, 0, stream>>>(W_ih, W_hh, wcomb,
                                      wih0f, whh0f, wih1f, whh1f, wcombf);
    wsplit_o<<<128, 256, 0, stream>>>(W_out, wfOf);

    persist<<<dim3(256), dim3(256), 0, stream>>>(
        xh, wih0f, whh0f, wih1f, whh1f, wcombf, wfOf,
        b_ih, b_hh, b_out, bcomb, h0c_all, h1_all, out, roster, bar);
}

// Round 16
// 3342.536 us; speedup vs baseline: 2.3612x; 1.1821x over previous
//
#include <hip/hip_runtime.h>
#include <math.h>

// TemporalDecoder round 16: L2-localized sync + h-exchange.
// R15 showed per-phase cost is pure LLC latency (agent-scope ops). All h data
// and barrier slots are intra-XCD -> serve them from the XCD's L2:
//   - h stores/loads: PLAIN (stores are write-around-L1 -> local L2)
//   - L1 staleness fixed by `buffer_inv` (L1-only invalidate) in the barrier
//     poll loop -- NOT R10's agent fence (which nuked L2).
//   - barrier: plain slot store + wave0 scan w/ buffer_inv + volatile loads.
// Replay-safe: end-of-dispatch flushes L2. f16-hi weights (R15-proven).

#define SS 128
#define NSTEPS 32
#define T 32

typedef __attribute__((ext_vector_type(8))) _Float16 f16x8;
typedef __attribute__((ext_vector_type(4))) float f32x4;

// ---------------- prep kernels ------------------------------------------------
__global__ __launch_bounds__(256) void xcvt(const float* __restrict__ x,
                                            ushort* __restrict__ xh, int n8) {
    int t = blockIdx.x * 256 + threadIdx.x;
    if (t >= n8) return;
    size_t i = (size_t)t * 8;
    float4 a = *(const float4*)(x + i), b = *(const float4*)(x + i + 4);
    union { _Float16 h[8]; uint4 u; } P;
    P.h[0] = (_Float16)a.x; P.h[1] = (_Float16)a.y;
    P.h[2] = (_Float16)a.z; P.h[3] = (_Float16)a.w;
    P.h[4] = (_Float16)b.x; P.h[5] = (_Float16)b.y;
    P.h[6] = (_Float16)b.z; P.h[7] = (_Float16)b.w;
    *(uint4*)(xh + i) = P.u;
}

// frag-split 5 K=512 matrices, f16-hi only.
// layout dst[cs 0..31][wn 0..3][kfg 0..15][lane 0..63][8]  (64KB per cs-slice)
__global__ __launch_bounds__(256) void wsplit5(
    const float* __restrict__ W_ih, const float* __restrict__ W_hh,
    const float* __restrict__ wcomb,
    ushort* __restrict__ wih0, ushort* __restrict__ whh0,
    ushort* __restrict__ wih1, ushort* __restrict__ whh1,
    ushort* __restrict__ wcmb)
{
    int f = blockIdx.x * 256 + threadIdx.x;      // 5 * 131072
    int mat = f >> 17;
    int t = f & 131071;
    int lane = t & 63;
    int kfg = (t >> 6) & 15;
    int wn = (t >> 10) & 3;
    int cs = t >> 12;
    int nloc = lane & 15;
    int g = nloc & 3, hcl = nloc >> 2;
    int n_W = g * 512 + cs * 16 + wn * 4 + hcl;
    int k = kfg * 32 + (lane >> 4) * 8;
    const float* src; ushort* dst;
    const size_t L1OFF = (size_t)2048 * 512;
    switch (mat) {
      case 0: src = W_ih + (size_t)n_W * 512 + k;         dst = wih0; break;
      case 1: src = W_hh + (size_t)n_W * 512 + k;         dst = whh0; break;
      case 2: src = W_ih + L1OFF + (size_t)n_W * 512 + k; dst = wih1; break;
      case 3: src = W_hh + L1OFF + (size_t)n_W * 512 + k; dst = whh1; break;
      default: src = wcomb + (size_t)n_W * 512 + k;       dst = wcmb; break;
    }
    float4 a = *(const float4*)src;
    float4 b = *(const float4*)(src + 4);
    float v[8] = {a.x, a.y, a.z, a.w, b.x, b.y, b.z, b.w};
    union { _Float16 h[8]; uint4 u; } Hi;
    #pragma unroll
    for (int j = 0; j < 8; ++j) Hi.h[j] = (_Float16)v[j];
    size_t b0 = (((size_t)cs * 4 + wn) * 16 + kfg) * 512 + lane * 8;
    *(uint4*)(dst + b0) = Hi.u;
}

// Wout frag hi-only: [cs][kfg][lane][8]; out-col = cs*16 + (lane&15)
__global__ __launch_bounds__(256) void wsplit_o(
    const float* __restrict__ W_out, ushort* __restrict__ wfO)
{
    int f = blockIdx.x * 256 + threadIdx.x;      // 32768
    int lane = f & 63;
    int kfg = (f >> 6) & 15;
    int cs = f >> 10;
    int col = cs * 16 + (lane & 15);
    int k = kfg * 32 + (lane >> 4) * 8;
    const float* src = W_out + (size_t)col * 512 + k;
    float4 a = *(const float4*)src;
    float4 b = *(const float4*)(src + 4);
    float v[8] = {a.x, a.y, a.z, a.w, b.x, b.y, b.z, b.w};
    union { _Float16 h[8]; uint4 u; } Hi;
    #pragma unroll
    for (int j = 0; j < 8; ++j) Hi.h[j] = (_Float16)v[j];
    size_t b0 = ((size_t)cs * 16 + kfg) * 512 + lane * 8;
    *(uint4*)(wfO + b0) = Hi.u;
}

// Wcomb = Wih0 @ Wout (fp32)
__global__ __launch_bounds__(256) void gemm_wcomb(
    const float* __restrict__ A, const float* __restrict__ Bm, float* __restrict__ C)
{
    __shared__ float sAf[64][17];
    __shared__ float sBf[16][65];
    const int tid = threadIdx.x;
    const int tx = tid & 15, ty = tid >> 4;
    const int n0 = blockIdx.x * 64, h0 = blockIdx.y * 64;
    float acc[4][4] = {};
    #pragma unroll 1
    for (int k0 = 0; k0 < 512; k0 += 16) {
        __syncthreads();
        {
            int r = tid >> 2, c = (tid & 3) * 4;
            float4 v = *(const float4*)&A[(size_t)(n0 + r) * 512 + k0 + c];
            sAf[r][c] = v.x; sAf[r][c+1] = v.y; sAf[r][c+2] = v.z; sAf[r][c+3] = v.w;
        }
        {
            int r = tid >> 4, c = (tid & 15) * 4;
            float4 v = *(const float4*)&Bm[(size_t)(k0 + r) * 512 + h0 + c];
            sBf[r][c] = v.x; sBf[r][c+1] = v.y; sBf[r][c+2] = v.z; sBf[r][c+3] = v.w;
        }
        __syncthreads();
        #pragma unroll
        for (int kk = 0; kk < 16; ++kk)
            #pragma unroll
            for (int a_ = 0; a_ < 4; ++a_) {
                float av = sAf[ty + 16*a_][kk];
                #pragma unroll
                for (int b_ = 0; b_ < 4; ++b_)
                    acc[a_][b_] += av * sBf[kk][tx + 16*b_];
            }
    }
    #pragma unroll
    for (int a_ = 0; a_ < 4; ++a_)
        #pragma unroll
        for (int b_ = 0; b_ < 4; ++b_)
            C[(size_t)(n0 + ty + 16*a_) * 512 + h0 + tx + 16*b_] = acc[a_][b_];
}

__global__ __launch_bounds__(256) void bcomb_k(const float* __restrict__ Wih0,
                                               const float* __restrict__ bout,
                                               float* __restrict__ bc) {
    int n = blockIdx.x * 256 + threadIdx.x;
    float a = 0.f;
    for (int f = 0; f < 512; ++f) a += Wih0[(size_t)n * 512 + f] * bout[f];
    bc[n] = a;
}

// ---------------- device helpers ---------------------------------------------
__device__ __forceinline__ void wgbar() {
    __builtin_amdgcn_sched_barrier(0);
    asm volatile("s_waitcnt lgkmcnt(0)" ::: "memory");
    __builtin_amdgcn_s_barrier();
    asm volatile("" ::: "memory");
    __builtin_amdgcn_sched_barrier(0);
}

// intra-XCD barrier, all L2-local:
// plain slot store (write-around L1 -> local L2); wave0 scans 32 slots with
// buffer_inv (L1-only invalidate) + volatile plain loads. On exit the CU's L1
// holds no stale h lines (last poll round's buffer_inv preceded its loads).
__device__ __forceinline__ void xbar(volatile unsigned* slots, unsigned phase, int cs) {
    __syncthreads();                     // drains vmcnt: plain h-stores in L2
    if (threadIdx.x == 0) slots[cs] = phase;
    if (threadIdx.x < 64) {
        unsigned v;
        do {
            asm volatile("buffer_inv" ::: "memory");
            v = (threadIdx.x < 32) ? slots[threadIdx.x] : phase;
        } while (!__all((int)(v >= phase)));
    }
    __syncthreads();
}

// load one 256-k chunk of a 32-row f16 A into regs (plain cached 16B loads)
__device__ __forceinline__ void ldChunk(uint4 (&u)[4], const ushort* src,
                                        size_t ld, int k0) {
    const int t = threadIdx.x;
    const int row = t >> 3;
    const int cg0 = (t & 7) * 4;
    const ushort* s = src + (size_t)row * ld + k0 + cg0 * 8;
    #pragma unroll
    for (int q = 0; q < 4; ++q) u[q] = *(const uint4*)(s + q * 8);
}
__device__ __forceinline__ void wrChunk(const uint4 (&u)[4], ushort (*sAb)[256]) {
    const int t = threadIdx.x;
    const int row = t >> 3;
    const int cg0 = (t & 7) * 4;
    #pragma unroll
    for (int q = 0; q < 4; ++q) {
        int cg = cg0 + q;
        int slot = (cg & 24) | ((cg ^ row) & 7);
        *(uint4*)&sAb[row][slot * 8] = u[q];
    }
}

// ---------------- the unified LSTM/fc step ------------------------------------
// gates = bias + B1(K=512)@A1 + B2(K=512)@A2 ; cell ; optional fc from A1(=h1)
// BLDS: B1=sW[0], B2=sW[1] (LDS-resident). else B1/B2 streamed to regs.
template<bool BLDS, bool FC, bool CARRY>
static __device__ __forceinline__ void do_step(
    const ushort* A1, size_t ld1, const ushort* A2,
    const ushort* B1s, const ushort* B2s,
    ushort (*sW)[4][16][512], ushort (*sA)[32][256],
    float* cReg, float biasv, ushort* Hout, ushort* Hcarry,
    const ushort* wfO_cs, float bofc, float* outp, int s, int xrow0,
    int lane, int wn, int cs)
{
    const int lr = lane & 15, lq = lane >> 4;

    // ---- depth-3 A register ring, issued FIRST (chunks: 0,1 from A1; 2,3 A2)
    uint4 ur[3][4];
    auto ldc = [&](int c) {
        const ushort* src = (c < 2) ? A1 : A2;
        size_t ld = (c < 2) ? ld1 : (size_t)512;
        ldChunk(ur[c % 3], src, ld, (c & 1) * 256);
    };
    ldc(0); ldc(1); ldc(2);

    // ---- streamed-B prefetch (decode-A only): B1 + fc now, B2 deferred to c==1
    f16x8 pb1[16], pb2[16], po[16];
    if constexpr (!BLDS) {
        #pragma unroll
        for (int kfg = 0; kfg < 16; ++kfg)
            pb1[kfg] = *(const f16x8*)(B1s + (((size_t)wn) * 16 + kfg) * 512 + lane * 8);
    }
    if constexpr (FC) {
        if (wn < 2) {
            #pragma unroll
            for (int kfg = 0; kfg < 16; ++kfg)
                po[kfg] = *(const f16x8*)(wfO_cs + (size_t)kfg * 512 + lane * 8);
        }
    }

    f32x4 acch[2], fch;
    #pragma unroll
    for (int m = 0; m < 2; ++m) acch[m] = (f32x4){biasv, biasv, biasv, biasv};
    if constexpr (FC) fch = (f32x4){bofc, bofc, bofc, bofc};

    wrChunk(ur[0], sA[0]);

    #pragma unroll
    for (int c = 0; c < 4; ++c) {
        wgbar();                          // sA[c&1] ready; ring loads in flight
        if constexpr (!BLDS) {
            if (c == 1) {                 // B2 prefetch under c=1 compute
                #pragma unroll
                for (int kfg = 0; kfg < 16; ++kfg)
                    pb2[kfg] = *(const f16x8*)(B2s + (((size_t)wn) * 16 + kfg) * 512 + lane * 8);
            }
        }
        if (c + 3 < 4) ldc(c + 3);
        if (c + 1 < 4) wrChunk(ur[(c + 1) % 3], sA[(c + 1) & 1]);
        const int bufc = c & 1;
        #pragma unroll
        for (int kf = 0; kf < 8; ++kf) {
            const int kfg = (c & 1) * 8 + kf;
            f16x8 bh;
            if constexpr (BLDS) {
                bh = *(const f16x8*)&sW[(c < 2) ? 0 : 1][wn][kfg][lane * 8];
            } else {
                bh = (c < 2) ? pb1[kfg] : pb2[kfg];
            }
            #pragma unroll
            for (int m = 0; m < 2; ++m) {
                int row = m * 16 + lr;
                int cg = kf * 4 + lq;
                int slot = (cg & 24) | ((cg ^ row) & 7);
                f16x8 a = *(const f16x8*)(&sA[bufc][row][0] + slot * 8);
                acch[m] = __builtin_amdgcn_mfma_f32_16x16x32_f16(a, bh, acch[m], 0, 0, 0);
            }
            if constexpr (FC) {
                if (wn < 2 && c < 2) {
                    int row = wn * 16 + lr;
                    int cg = kf * 4 + lq;
                    int slot = (cg & 24) | ((cg ^ row) & 7);
                    f16x8 a = *(const f16x8*)(&sA[bufc][row][0] + slot * 8);
                    fch = __builtin_amdgcn_mfma_f32_16x16x32_f16(a, po[kfg], fch, 0, 0, 0);
                }
            }
        }
    }

    // cell epilogue (plain 8B packed h-stores -> local L2)
    const int nloc = lane & 15;
    const int g = nloc & 3;
    const int colb = cs * 16 + wn * 4;
    #pragma unroll
    for (int m = 0; m < 2; ++m) {
        #pragma unroll
        for (int j = 0; j < 4; ++j) {
            float v = acch[m][j];
            float s1 = __shfl_xor(v, 1, 64);
            float s2 = __shfl_xor(v, 2, 64);
            float s3 = __shfl_xor(v, 3, 64);
            float sel0 = v;
            auto selk = [&](int k) { return (k==0)?sel0:(k==1)?s1:(k==2)?s2:s3; };
            float pi = selk(g), pf = selk(g ^ 1), pg = selk(g ^ 2), po_ = selk(g ^ 3);
            float ig = 1.f / (1.f + __expf(-pi));
            float fg = 1.f / (1.f + __expf(-pf));
            float e2g = __expf(2.f * fminf(fmaxf(pg, -20.f), 20.f));
            float gg = (e2g - 1.f) / (e2g + 1.f);
            float og = 1.f / (1.f + __expf(-po_));
            float cn = fg * cReg[m * 4 + j] + ig * gg;
            cReg[m * 4 + j] = cn;
            float e2c = __expf(2.f * fminf(fmaxf(cn, -20.f), 20.f));
            float th = (e2c - 1.f) / (e2c + 1.f);
            float hn = og * th;
            union { _Float16 h; ushort u; } P; P.h = (_Float16)hn;
            int hb = (int)P.u;
            int base = lane & ~15;
            int b1 = __shfl(hb, base + 4, 64);
            int b2 = __shfl(hb, base + 8, 64);
            int b3 = __shfl(hb, base + 12, 64);
            if (lr == 0) {
                unsigned long long pk =
                    (unsigned long long)(unsigned)(hb & 0xFFFF)
                    | ((unsigned long long)(unsigned)(b1 & 0xFFFF) << 16)
                    | ((unsigned long long)(unsigned)(b2 & 0xFFFF) << 32)
                    | ((unsigned long long)(unsigned)(b3 & 0xFFFF) << 48);
                int row = m * 16 + lq * 4 + j;
                *(unsigned long long*)&Hout[(size_t)row * 512 + colb] = pk;
                if constexpr (CARRY)
                    *(unsigned long long*)&Hcarry[(size_t)row * 512 + colb] = pk;
            }
        }
    }
    if constexpr (FC) {
        if (wn < 2) {
            #pragma unroll
            for (int j = 0; j < 4; ++j) {
                float v = fch[j];
                int row = wn * 16 + lq * 4 + j;
                outp[((size_t)(xrow0 + row) * NSTEPS + s) * 512 + cs * 16 + lr] = v;
            }
        }
    }
}

// ---------------- persistent kernel ------------------------------------------
__global__ __launch_bounds__(256, 1) void persist(
    const ushort* __restrict__ xh,
    const ushort* __restrict__ wih0f, const ushort* __restrict__ whh0f,
    const ushort* __restrict__ wih1f, const ushort* __restrict__ whh1f,
    const ushort* __restrict__ wcombf, const ushort* __restrict__ wfOf,
    const float* __restrict__ b_ih, const float* __restrict__ b_hh,
    const float* __restrict__ b_out, const float* __restrict__ bcomb,
    ushort* h0c_all, ushort* h1_all,
    float* out, unsigned* roster, unsigned* bar)
{
    __shared__ ushort sW[2][4][16][512];      // 128KB: [mat][wn][kfg][lane*8]
    __shared__ ushort sA[2][32][256];         // 32KB

    const int tid = threadIdx.x;
    if (tid == 0) {
        int xid;
        asm volatile("s_getreg_b32 %0, hwreg(HW_REG_XCC_ID)" : "=s"(xid));
        xid &= 7;
        unsigned slot = atomicAdd(&roster[xid * 16], 1u) & 31u;
        *(int*)&sA[0][0][0] = xid * 32 + (int)slot;
    }
    __syncthreads();
    const int packed = *(const int*)&sA[0][0][0];
    __syncthreads();
    const int xcd = packed >> 5, cs = packed & 31;
    const int xrow0 = xcd * 32;

    ushort* h0c = h0c_all + (size_t)xcd * 33 * 32 * 512;
    ushort* h1r = h1_all + (size_t)xcd * 2 * 32 * 512;
    volatile unsigned* slots = bar + xcd * 32;

    const int lane = tid & 63, wn = tid >> 6;
    const int nloc = lane & 15, g = nloc & 3, hcl = nloc >> 2;
    const int gcol = g * 512 + cs * 16 + wn * 4 + hcl;
    const float b0v = b_ih[gcol] + b_hh[gcol];
    const float b1v = b_ih[2048 + gcol] + b_hh[2048 + gcol];
    const float b0d = b0v + bcomb[gcol];
    const float bofc = b_out[cs * 16 + nloc];

    const ushort* wih0cs = wih0f + (size_t)cs * 32768;
    const ushort* whh0cs = whh0f + (size_t)cs * 32768;
    const ushort* wih1cs = wih1f + (size_t)cs * 32768;
    const ushort* whh1cs = whh1f + (size_t)cs * 32768;
    const ushort* wcombcs = wcombf + (size_t)cs * 32768;
    const ushort* wfOcs = wfOf + (size_t)cs * 8192;

    auto fillW2 = [&](const ushort* w1, const ushort* w2) {
        const uint4* s1 = (const uint4*)w1;
        const uint4* s2 = (const uint4*)w2;
        uint4* d1 = (uint4*)&sW[0][0][0][0];
        uint4* d2 = (uint4*)&sW[1][0][0][0];
        #pragma unroll 1
        for (int i = tid; i < 4096; i += 256) { d1[i] = s1[i]; d2[i] = s2[i]; }
        __syncthreads();
    };

    float c0[8], c1[8];
    #pragma unroll
    for (int i = 0; i < 8; ++i) { c0[i] = 0.f; c1[i] = 0.f; }
    unsigned ph = 0;
    int cur = 0;

    // ---- encode: 4 chunks x (32 L0 steps, 32 L1 steps), layer-sequential ----
    #pragma unroll 1
    for (int ch = 0; ch < 4; ++ch) {
        fillW2(wih0cs, whh0cs);
        #pragma unroll 1
        for (int ti = 0; ti < T; ++ti) {
            int t = ch * T + ti;
            const ushort* xA = xh + ((size_t)xrow0 * SS + t) * 512;
            if (ti == T - 1)
                do_step<true, false, true>(xA, (size_t)SS * 512,
                    h0c + (size_t)ti * 32 * 512, nullptr, nullptr, sW, sA,
                    c0, b0v, h0c + (size_t)(ti + 1) * 32 * 512, h0c,
                    nullptr, 0.f, nullptr, 0, xrow0, lane, wn, cs);
            else
                do_step<true, false, false>(xA, (size_t)SS * 512,
                    h0c + (size_t)ti * 32 * 512, nullptr, nullptr, sW, sA,
                    c0, b0v, h0c + (size_t)(ti + 1) * 32 * 512, nullptr,
                    nullptr, 0.f, nullptr, 0, xrow0, lane, wn, cs);
            xbar(slots, ++ph, cs);
        }
        fillW2(wih1cs, whh1cs);
        #pragma unroll 1
        for (int ti = 0; ti < T; ++ti) {
            do_step<true, false, false>(
                h0c + (size_t)(ti + 1) * 32 * 512, 512,
                h1r + (size_t)cur * 32 * 512, nullptr, nullptr, sW, sA,
                c1, b1v, h1r + (size_t)(cur ^ 1) * 32 * 512, nullptr,
                nullptr, 0.f, nullptr, 0, xrow0, lane, wn, cs);
            cur ^= 1;
            xbar(slots, ++ph, cs);
        }
    }

    // ---- decode: phase A {L0'+fc, streamed B}; phase B {L1, LDS-resident} ----
    fillW2(wih1cs, whh1cs);       // L1 weights stay resident all decode
    int c0i = 0;
    #pragma unroll 1
    for (int s = 0; s < NSTEPS; ++s) {
        do_step<false, true, false>(
            h1r + (size_t)cur * 32 * 512, 512,
            h0c + (size_t)c0i * 32 * 512, wcombcs, whh0cs, sW, sA,
            c0, b0d, h0c + (size_t)(c0i ^ 1) * 32 * 512, nullptr,
            wfOcs, bofc, out, s, xrow0, lane, wn, cs);
        xbar(slots, ++ph, cs);
        c0i ^= 1;
        if (s == NSTEPS - 1) break;
        do_step<true, false, false>(
            h0c + (size_t)c0i * 32 * 512, 512,
            h1r + (size_t)cur * 32 * 512, nullptr, nullptr, sW, sA,
            c1, b1v, h1r + (size_t)(cur ^ 1) * 32 * 512, nullptr,
            nullptr, 0.f, nullptr, 0, xrow0, lane, wn, cs);
        cur ^= 1;
        xbar(slots, ++ph, cs);
    }
}

// ---------------- host ---------------------------------------------------------
extern "C" void kernel_launch(void* const* d_in, const int* in_sizes, int n_in,
                              void* d_out, int out_size, void* d_ws, size_t ws_size,
                              hipStream_t stream)
{
    const float* x     = (const float*)d_in[0];
    const float* W_ih  = (const float*)d_in[1];
    const float* W_hh  = (const float*)d_in[2];
    const float* b_ih  = (const float*)d_in[3];
    const float* b_hh  = (const float*)d_in[4];
    const float* W_out = (const float*)d_in[5];
    const float* b_out = (const float*)d_in[6];
    float* out = (float*)d_out;
    (void)n_in; (void)out_size; (void)ws_size;

    char* ws = (char*)d_ws;
    unsigned* roster = (unsigned*)(ws + 0);              // 8 ctrs, 64B apart
    unsigned* bar    = (unsigned*)(ws + 512);            // 8 XCDs x 32 slots
    ushort* h0c_all  = (ushort*)(ws + 8192);             // 8*33*32*512*2 = 8,650,752
    ushort* h1_all   = (ushort*)(ws + 8192 + 8650752);   // 8*2*32*512*2  = 524,288
    const size_t ZB  = 8192 + 8650752 + 524288;          // 9,183,232 zeroed
    ushort* wih0f  = (ushort*)(ws + ZB + 0 * 2097152);
    ushort* whh0f  = (ushort*)(ws + ZB + 1 * 2097152);
    ushort* wih1f  = (ushort*)(ws + ZB + 2 * 2097152);
    ushort* whh1f  = (ushort*)(ws + ZB + 3 * 2097152);
    ushort* wcombf = (ushort*)(ws + ZB + 4 * 2097152);
    ushort* wfOf   = (ushort*)(ws + ZB + 5 * 2097152);               // 512KB
    float*  wcomb  = (float*) (ws + ZB + 5 * 2097152 + 524288);      // 4MB
    float*  bcomb  = (float*) (ws + ZB + 5 * 2097152 + 524288 + 4194304);
    ushort* xh     = (ushort*)(ws + ZB + 5 * 2097152 + 524288 + 4194304 + 65536);
    // xh = 33.5MB; total ~57 MB

    (void)hipMemsetAsync(d_ws, 0, ZB, stream);
    {
        int n8 = (in_sizes[0] + 7) / 8;                  // 2,097,152
        int blocks = (n8 + 255) / 256;                   // 8192
        xcvt<<<blocks, 256, 0, stream>>>(x, xh, n8);
    }
    gemm_wcomb<<<dim3(32, 8), 256, 0, stream>>>(W_ih, W_out, wcomb);
    bcomb_k<<<8, 256, 0, stream>>>(W_ih, b_out, bcomb);
    wsplit5<<<2560, 256, 0, stream>>>(W_ih, W_hh, wcomb,
                                      wih0f, whh0f, wih1f, whh1f, wcombf);
    wsplit_o<<<128, 256, 0, stream>>>(W_out, wfOf);

    persist<<<dim3(256), dim3(256), 0, stream>>>(
        xh, wih0f, whh0f, wih1f, whh1f, wcombf, wfOf,
        b_ih, b_hh, b_out, bcomb, h0c_all, h1_all, out, roster, bar);
}